// Round 6
// baseline (1616.494 us; speedup 1.0000x reference)
//
#include <hip/hip_runtime.h>
#include <stdint.h>
#include <math.h>

// ---------------------------------------------------------------------------
// NanochatMiniLM forward on MI355X. Round 6: GEMM K-loop rebuilt as a
// depth-3 software pipeline over 4 LDS buffers with raw s_barrier +
// counted s_waitcnt vmcnt(N) (T4: loads stay in flight ACROSS barriers,
// never drained to 0 in the loop). One barrier per K-step; stage issued at
// the top of the step -> ~3 steps of HBM-latency cover.
// Split-K partial planes + fused reduction (R4), C^T epilogue, fast
// softcap, XCD swizzle retained.
// B=2 T=1024 D=1024 H=16 KV=4 HD=64 L=6 VP=32000, windows {256,1024,...}
// ---------------------------------------------------------------------------

using bf16x8 = __attribute__((ext_vector_type(8))) short;   // 8 bf16 (4 VGPRs)
using f32x4  = __attribute__((ext_vector_type(4))) float;   // 4 f32 acc

#define DEV static __device__ __forceinline__

DEV unsigned short f2bf(float f) {            // RNE f32 -> bf16 bits
  unsigned int x = __builtin_bit_cast(unsigned int, f);
  x += 0x7fffu + ((x >> 16) & 1u);
  return (unsigned short)(x >> 16);
}
DEV float bf2f(unsigned short u) {
  return __builtin_bit_cast(float, (unsigned int)u << 16);
}
DEV unsigned int packbf2(float a, float b) {
  return (unsigned int)f2bf(a) | ((unsigned int)f2bf(b) << 16);
}

// async global->LDS, 16B per lane; LDS dest is wave-uniform base + lane*16
DEV void gload16(const unsigned short* g, unsigned short* l) {
  __builtin_amdgcn_global_load_lds(
      (__attribute__((address_space(1))) void*)const_cast<unsigned short*>(g),
      (__attribute__((address_space(3))) void*)l, 16, 0, 0);
}

// ---------------------------- weight conversion ----------------------------

extern "C" __global__ __launch_bounds__(256)
void cvt_bf16_kernel(const float* __restrict__ src, unsigned short* __restrict__ dst, long n) {
  long i = ((long)blockIdx.x * 256 + threadIdx.x) * 8;
  if (i >= n) return;
  const float4 a = *reinterpret_cast<const float4*>(src + i);
  const float4 b = *reinterpret_cast<const float4*>(src + i + 4);
  uint4 u;
  u.x = packbf2(a.x, a.y); u.y = packbf2(a.z, a.w);
  u.z = packbf2(b.x, b.y); u.w = packbf2(b.z, b.w);
  *reinterpret_cast<uint4*>(dst + i) = u;
}

// pack Wq|Wk|Wv (per layer) into contiguous [1536][1024] bf16 rows
extern "C" __global__ __launch_bounds__(256)
void qkvw_pack_kernel(const float* __restrict__ Wq, const float* __restrict__ Wk,
                      const float* __restrict__ Wv, unsigned short* __restrict__ dst) {
  long i = ((long)blockIdx.x * 256 + threadIdx.x) * 8;
  if (i >= (long)6 * 1536 * 1024) return;
  int c = (int)(i & 1023);
  int row = (int)(i >> 10);
  int l = row / 1536, r = row - l * 1536;
  const float* src;
  if (r < 1024)      src = Wq + ((size_t)l * 1024 + r) * 1024 + c;
  else if (r < 1280) src = Wk + ((size_t)l * 256 + (r - 1024)) * 1024 + c;
  else               src = Wv + ((size_t)l * 256 + (r - 1280)) * 1024 + c;
  const float4 a = *reinterpret_cast<const float4*>(src);
  const float4 b = *reinterpret_cast<const float4*>(src + 4);
  uint4 u;
  u.x = packbf2(a.x, a.y); u.y = packbf2(a.z, a.w);
  u.z = packbf2(b.x, b.y); u.w = packbf2(b.z, b.w);
  *reinterpret_cast<uint4*>(dst + i) = u;
}

// ------------------------------- rope tables -------------------------------

extern "C" __global__ __launch_bounds__(256)
void rope_tab_kernel(float* __restrict__ cost, float* __restrict__ sint) {
  const int idx = blockIdx.x * 256 + threadIdx.x;   // t*32 + i, 32768 total
  const int t = idx >> 5, i = idx & 31;
  const double inv = exp(((double)i * (-1.0 / 32.0)) * log(100000.0));
  const double f = (double)t * inv;
  cost[idx] = (float)cos(f);
  sint[idx] = (float)sin(f);
}

// ------------------------- embedding + rms + smear -------------------------
// one wave per token; lane owns channels c = i*256 + lane*4 (i=0..3)

extern "C" __global__ __launch_bounds__(256)
void embed_kernel(const int* __restrict__ ids, const float* __restrict__ wte,
                  const float* __restrict__ smear_w, const float* __restrict__ smear_l,
                  float* __restrict__ x, float* __restrict__ x0) {
  const int wid = threadIdx.x >> 6, lane = threadIdx.x & 63;
  const int tok = blockIdx.x * 4 + wid;
  const int t = tok & 1023;
  const float eps = 1.1920929e-7f;

  const float* wrow = wte + (size_t)ids[tok] * 1024;
  float4 v[4];
  float ss = 0.f;
#pragma unroll
  for (int i = 0; i < 4; ++i) {
    v[i] = *reinterpret_cast<const float4*>(wrow + i * 256 + lane * 4);
    ss += v[i].x * v[i].x + v[i].y * v[i].y + v[i].z * v[i].z + v[i].w * v[i].w;
  }
#pragma unroll
  for (int m = 1; m < 64; m <<= 1) ss += __shfl_xor(ss, m);
  const float sc = 1.f / sqrtf(ss * (1.f / 1024.f) + eps);

  float4 pv[4];
#pragma unroll
  for (int i = 0; i < 4; ++i) { pv[i].x = 0.f; pv[i].y = 0.f; pv[i].z = 0.f; pv[i].w = 0.f; }
  float scp = 0.f, gate = 0.f;
  if (t > 0) {
    const float* prow = wte + (size_t)ids[tok - 1] * 1024;
    float ssp = 0.f;
#pragma unroll
    for (int i = 0; i < 4; ++i) {
      pv[i] = *reinterpret_cast<const float4*>(prow + i * 256 + lane * 4);
      ssp += pv[i].x * pv[i].x + pv[i].y * pv[i].y + pv[i].z * pv[i].z + pv[i].w * pv[i].w;
    }
#pragma unroll
    for (int m = 1; m < 64; m <<= 1) ssp += __shfl_xor(ssp, m);
    scp = 1.f / sqrtf(ssp * (1.f / 1024.f) + eps);
    // gate from own rms'd channels 0..23 (v[0] holds c = lane*4..lane*4+3)
    float gp = 0.f;
    if (lane < 6) {
      gp = v[0].x * smear_w[lane * 4] + v[0].y * smear_w[lane * 4 + 1] +
           v[0].z * smear_w[lane * 4 + 2] + v[0].w * smear_w[lane * 4 + 3];
      gp *= sc;
    }
#pragma unroll
    for (int m = 1; m < 64; m <<= 1) gp += __shfl_xor(gp, m);
    gate = smear_l[0] / (1.f + __expf(-gp));
  }
#pragma unroll
  for (int i = 0; i < 4; ++i) {
    const int c = i * 256 + lane * 4;
    float4 o;
    o.x = v[i].x * sc + gate * pv[i].x * scp;
    o.y = v[i].y * sc + gate * pv[i].y * scp;
    o.z = v[i].z * sc + gate * pv[i].z * scp;
    o.w = v[i].w * sc + gate * pv[i].w * scp;
    *reinterpret_cast<float4*>(x + (size_t)tok * 1024 + c) = o;
    *reinterpret_cast<float4*>(x0 + (size_t)tok * 1024 + c) = o;
  }
}

// ------------- residual mix + split-K partial reduce + rmsnorm -------------
// x <- a*(x + sum_{p<np} parts[p]) + b*x0   (a=1,b=0 when combine==0)
// writes x back when it changed; xn <- rms(x) in bf16.
// parts: np contiguous [2048][1024] f32 planes (plane stride 2048*1024).

extern "C" __global__ __launch_bounds__(256)
void rmsnorm_kernel(float* __restrict__ x, const float* __restrict__ x0,
                    const float* __restrict__ parts, int np,
                    const float* __restrict__ residc, const float* __restrict__ x0c,
                    int layer, int combine, unsigned short* __restrict__ xn) {
  const int wid = threadIdx.x >> 6, lane = threadIdx.x & 63;
  const int tok = blockIdx.x * 4 + wid;
  float* xr = x + (size_t)tok * 1024;
  const float* x0r = x0 + (size_t)tok * 1024;
  float a = 1.f, bb = 0.f;
  if (combine) { a = residc[layer]; bb = x0c[layer]; }
  float4 v[4];
  float ss = 0.f;
#pragma unroll
  for (int i = 0; i < 4; ++i) {
    const int c = i * 256 + lane * 4;
    float4 xv = *reinterpret_cast<const float4*>(xr + c);
    for (int pi = 0; pi < np; ++pi) {
      const float4 pv = *reinterpret_cast<const float4*>(
          parts + (size_t)pi * 2048 * 1024 + (size_t)tok * 1024 + c);
      xv.x += pv.x; xv.y += pv.y; xv.z += pv.z; xv.w += pv.w;
    }
    if (combine) {
      const float4 ov = *reinterpret_cast<const float4*>(x0r + c);
      xv.x = a * xv.x + bb * ov.x; xv.y = a * xv.y + bb * ov.y;
      xv.z = a * xv.z + bb * ov.z; xv.w = a * xv.w + bb * ov.w;
    }
    if (combine || np > 0) *reinterpret_cast<float4*>(xr + c) = xv;
    v[i] = xv;
    ss += xv.x * xv.x + xv.y * xv.y + xv.z * xv.z + xv.w * xv.w;
  }
#pragma unroll
  for (int m = 1; m < 64; m <<= 1) ss += __shfl_xor(ss, m);
  const float sc = 1.f / sqrtf(ss * (1.f / 1024.f) + 1.1920929e-7f);
#pragma unroll
  for (int i = 0; i < 4; ++i) {
    const int c = i * 256 + lane * 4;
    ushort4 u;
    u.x = f2bf(v[i].x * sc); u.y = f2bf(v[i].y * sc);
    u.z = f2bf(v[i].z * sc); u.w = f2bf(v[i].w * sc);
    *reinterpret_cast<ushort4*>(xn + (size_t)tok * 1024 + c) = u;
  }
}

// ------------------- qkv post: rope + rms + ve-gate -> bf16 ----------------
// one wave per token; lane owns 16 contiguous channels (head = lane/4).
// qkv arrives as TWO split-K partial planes (qkv0 + qkv1), summed here.

extern "C" __global__ __launch_bounds__(256)
void qkv_post_kernel(const float* __restrict__ qkv0, const float* __restrict__ qkv1,
                     const unsigned short* __restrict__ xn,
                     const int* __restrict__ ids,
                     const float* __restrict__ ve_tab, const float* __restrict__ ve_gate_w,
                     const float* __restrict__ cost, const float* __restrict__ sint,
                     unsigned short* __restrict__ qb, unsigned short* __restrict__ kbuf,
                     unsigned short* __restrict__ vb) {
  const int wid = threadIdx.x >> 6, lane = threadIdx.x & 63;
  const int tok = blockIdx.x * 4 + wid;
  const int t = tok & 1023;
  const float eps = 1.1920929e-7f;
  const float* rowA = qkv0 + (size_t)tok * 1536;
  const float* rowB = qkv1 + (size_t)tok * 1536;
  const bool x1half = (lane & 2) == 0;   // lane%4 in {0,1}: x1; {2,3}: x2
  const int i0 = (lane & 1) << 4;        // rotary index base within half

  // ---- Q: 16 heads * 64, scale = 1.2/8 folded in ----
  {
    float v[16], p[16];
    {
      const float4* ra = reinterpret_cast<const float4*>(rowA + lane * 16);
      const float4* rb = reinterpret_cast<const float4*>(rowB + lane * 16);
#pragma unroll
      for (int i = 0; i < 4; ++i) {
        const float4 qa = ra[i], qb4 = rb[i];
        v[i * 4] = qa.x + qb4.x; v[i * 4 + 1] = qa.y + qb4.y;
        v[i * 4 + 2] = qa.z + qb4.z; v[i * 4 + 3] = qa.w + qb4.w;
      }
    }
#pragma unroll
    for (int i = 0; i < 16; ++i) p[i] = __shfl_xor(v[i], 2);
    float out[16]; float ssq = 0.f;
#pragma unroll
    for (int i = 0; i < 16; ++i) {
      const float c = cost[t * 32 + i0 + i];
      const float s = sint[t * 32 + i0 + i];
      out[i] = x1half ? (v[i] * c + p[i] * s) : (v[i] * c - p[i] * s);
      ssq += out[i] * out[i];
    }
    ssq += __shfl_xor(ssq, 1);
    ssq += __shfl_xor(ssq, 2);
    const float sc = 0.15f / sqrtf(ssq * (1.f / 64.f) + eps);
#pragma unroll
    for (int i = 0; i < 16; i += 4) {
      ushort4 u;
      u.x = f2bf(out[i] * sc); u.y = f2bf(out[i + 1] * sc);
      u.z = f2bf(out[i + 2] * sc); u.w = f2bf(out[i + 3] * sc);
      *reinterpret_cast<ushort4*>(qb + (size_t)tok * 1024 + lane * 16 + i) = u;
    }
  }
  const int kl = lane & 15;  // lanes 16-63 mirror 0-15 (keeps shfl uniform)
  // ---- K: 4 kv heads * 64, scale 1.2 ----
  {
    float v[16], p[16];
    {
      const float4* ra = reinterpret_cast<const float4*>(rowA + 1024 + kl * 16);
      const float4* rb = reinterpret_cast<const float4*>(rowB + 1024 + kl * 16);
#pragma unroll
      for (int i = 0; i < 4; ++i) {
        const float4 qa = ra[i], qb4 = rb[i];
        v[i * 4] = qa.x + qb4.x; v[i * 4 + 1] = qa.y + qb4.y;
        v[i * 4 + 2] = qa.z + qb4.z; v[i * 4 + 3] = qa.w + qb4.w;
      }
    }
#pragma unroll
    for (int i = 0; i < 16; ++i) p[i] = __shfl_xor(v[i], 2);
    float out[16]; float ssq = 0.f;
#pragma unroll
    for (int i = 0; i < 16; ++i) {
      const float c = cost[t * 32 + i0 + i];
      const float s = sint[t * 32 + i0 + i];
      out[i] = x1half ? (v[i] * c + p[i] * s) : (v[i] * c - p[i] * s);
      ssq += out[i] * out[i];
    }
    ssq += __shfl_xor(ssq, 1);
    ssq += __shfl_xor(ssq, 2);
    const float sc = 1.2f / sqrtf(ssq * (1.f / 64.f) + eps);
    if (lane < 16) {
#pragma unroll
      for (int i = 0; i < 16; i += 4) {
        ushort4 u;
        u.x = f2bf(out[i] * sc); u.y = f2bf(out[i + 1] * sc);
        u.z = f2bf(out[i + 2] * sc); u.w = f2bf(out[i + 3] * sc);
        *reinterpret_cast<ushort4*>(kbuf + (size_t)tok * 256 + kl * 16 + i) = u;
      }
    }
  }
  // ---- V: optional value-embedding gate ----
  {
    float v[16];
    {
      const float4* ra = reinterpret_cast<const float4*>(rowA + 1280 + kl * 16);
      const float4* rb = reinterpret_cast<const float4*>(rowB + 1280 + kl * 16);
#pragma unroll
      for (int i = 0; i < 4; ++i) {
        const float4 qa = ra[i], qb4 = rb[i];
        v[i * 4] = qa.x + qb4.x; v[i * 4 + 1] = qa.y + qb4.y;
        v[i * 4 + 2] = qa.z + qb4.z; v[i * 4 + 3] = qa.w + qb4.w;
      }
    }
    if (ve_tab != nullptr) {
      const int kvh = kl >> 2;
      float g = 0.f;
#pragma unroll
      for (int c = 0; c < 12; ++c)
        g += bf2f(xn[(size_t)tok * 1024 + c]) * ve_gate_w[kvh * 12 + c];
      g = 3.f / (1.f + __expf(-g));
      const float* ver = ve_tab + (size_t)ids[tok] * 256 + kl * 16;
#pragma unroll
      for (int i = 0; i < 16; ++i) v[i] += g * ver[i];
    }
    if (lane < 16) {
#pragma unroll
      for (int i = 0; i < 16; i += 4) {
        ushort4 u;
        u.x = f2bf(v[i]); u.y = f2bf(v[i + 1]); u.z = f2bf(v[i + 2]); u.w = f2bf(v[i + 3]);
        *reinterpret_cast<ushort4*>(vb + (size_t)tok * 256 + kl * 16 + i) = u;
      }
    }
  }
}

// ---------------- V transpose: vb[b][t][kv*64+d] -> vt[b*4+kv][d][t] -------

extern "C" __global__ __launch_bounds__(256)
void vtrans_kernel(const unsigned short* __restrict__ vb, unsigned short* __restrict__ vt) {
  __shared__ unsigned short tile[64][72];
  const int t0 = blockIdx.x << 6;
  const int bk = blockIdx.y;               // b*4 + kv
  const int tid = threadIdx.x;
  {
    const int r = tid >> 2, cs = (tid & 3) << 4;
    const unsigned short* src = vb + ((size_t)((bk >> 2) * 1024 + t0 + r)) * 256 + (bk & 3) * 64 + cs;
    *reinterpret_cast<uint4*>(&tile[r][cs]) = *reinterpret_cast<const uint4*>(src);
    *reinterpret_cast<uint4*>(&tile[r][cs + 8]) = *reinterpret_cast<const uint4*>(src + 8);
  }
  __syncthreads();
  {
    const int d = tid >> 2, ts = (tid & 3) << 4;
    unsigned int w[8];
#pragma unroll
    for (int i = 0; i < 8; ++i)
      w[i] = (unsigned int)tile[ts + 2 * i][d] | ((unsigned int)tile[ts + 2 * i + 1][d] << 16);
    unsigned short* dst = vt + ((size_t)bk * 64 + d) * 1024 + t0 + ts;
    uint4 u0; u0.x = w[0]; u0.y = w[1]; u0.z = w[2]; u0.w = w[3];
    uint4 u1; u1.x = w[4]; u1.y = w[5]; u1.z = w[6]; u1.w = w[7];
    *reinterpret_cast<uint4*>(dst) = u0;
    *reinterpret_cast<uint4*>(dst + 8) = u1;
  }
}

// --------------------------- flash attention -------------------------------
// 1 wave per (b, h, 16-query block). Swapped QK^T: St[key][query] via
// mfma(K, Q); softmax reduce over lane groups; P -> LDS -> PV A-operand;
// V^T rows give contiguous PV B-operand.

extern "C" __global__ __launch_bounds__(64)
void attn_kernel(const unsigned short* __restrict__ qb,
                 const unsigned short* __restrict__ kb,
                 const unsigned short* __restrict__ vt,
                 unsigned short* __restrict__ y, int W) {
  __shared__ unsigned short p_lds[16 * 32];
  const int lane = threadIdx.x;
  const int q0 = blockIdx.x << 4;
  const int h = blockIdx.y;
  const int b = blockIdx.z;
  const int kv = h >> 2;
  const int lr = lane & 15, lk = lane >> 4;

  bf16x8 qf0, qf1;
  {
    const unsigned short* qrow = qb + ((size_t)(b * 1024 + q0 + lr)) * 1024 + h * 64 + (lk << 3);
    qf0 = *reinterpret_cast<const bf16x8*>(qrow);
    qf1 = *reinterpret_cast<const bf16x8*>(qrow + 32);
  }
  f32x4 acc[4] = {};
  float m_run = -3e38f, l_run = 0.f;
  int kstart = q0 - W + 1; if (kstart < 0) kstart = 0;
  kstart &= ~31;
  const int qq = q0 + lr;

  for (int kb0 = kstart; kb0 < q0 + 16; kb0 += 32) {
    f32x4 st[2];
#pragma unroll
    for (int s = 0; s < 2; ++s) {
      const unsigned short* krow = kb + ((size_t)(b * 1024 + kb0 + (s << 4) + lr)) * 256 + kv * 64 + (lk << 3);
      bf16x8 kf0 = *reinterpret_cast<const bf16x8*>(krow);
      bf16x8 kf1 = *reinterpret_cast<const bf16x8*>(krow + 32);
      f32x4 z = {0.f, 0.f, 0.f, 0.f};
      z = __builtin_amdgcn_mfma_f32_16x16x32_bf16(kf0, qf0, z, 0, 0, 0);
      st[s] = __builtin_amdgcn_mfma_f32_16x16x32_bf16(kf1, qf1, z, 0, 0, 0);
    }
    float sv[8];
    float bm = -3e38f;
#pragma unroll
    for (int s = 0; s < 2; ++s)
#pragma unroll
      for (int j = 0; j < 4; ++j) {
        const int key = kb0 + (s << 4) + (lk << 2) + j;
        const bool valid = (key <= qq) && (qq - key < W);
        const float xx = valid ? st[s][j] : -3e38f;
        sv[s * 4 + j] = xx;
        bm = fmaxf(bm, xx);
      }
    bm = fmaxf(bm, __shfl_xor(bm, 16));
    bm = fmaxf(bm, __shfl_xor(bm, 32));
    const float m_new = fmaxf(m_run, bm);
    const float alpha = __expf(m_run - m_new);
    float psum = 0.f;
    unsigned short pbv[8];
#pragma unroll
    for (int s = 0; s < 2; ++s)
#pragma unroll
      for (int j = 0; j < 4; ++j) {
        const int key = kb0 + (s << 4) + (lk << 2) + j;
        const bool valid = (key <= qq) && (qq - key < W);
        const float pv = valid ? __expf(sv[s * 4 + j] - m_new) : 0.f;
        psum += pv;
        pbv[s * 4 + j] = f2bf(pv);
      }
    psum += __shfl_xor(psum, 16);
    psum += __shfl_xor(psum, 32);
    l_run = l_run * alpha + psum;
    m_run = m_new;

    __syncthreads();  // WAR vs previous iteration's reads
    {
      ushort4 u0, u1;
      u0.x = pbv[0]; u0.y = pbv[1]; u0.z = pbv[2]; u0.w = pbv[3];
      u1.x = pbv[4]; u1.y = pbv[5]; u1.z = pbv[6]; u1.w = pbv[7];
      *reinterpret_cast<ushort4*>(p_lds + lr * 32 + (lk << 2)) = u0;
      *reinterpret_cast<ushort4*>(p_lds + lr * 32 + 16 + (lk << 2)) = u1;
    }
    __syncthreads();
    const bf16x8 pf = *reinterpret_cast<const bf16x8*>(p_lds + lr * 32 + (lk << 3));
    float al[4];
#pragma unroll
    for (int j = 0; j < 4; ++j) al[j] = __shfl(alpha, (lk << 2) + j);
#pragma unroll
    for (int d = 0; d < 4; ++d) {
      const unsigned short* vrow = vt + ((size_t)((b * 4 + kv) * 64 + (d << 4) + lr)) * 1024 + kb0 + (lk << 3);
      const bf16x8 vf = *reinterpret_cast<const bf16x8*>(vrow);
#pragma unroll
      for (int j = 0; j < 4; ++j) acc[d][j] *= al[j];
      acc[d] = __builtin_amdgcn_mfma_f32_16x16x32_bf16(pf, vf, acc[d], 0, 0, 0);
    }
  }
  float linv[4];
#pragma unroll
  for (int j = 0; j < 4; ++j) linv[j] = 1.f / __shfl(l_run, (lk << 2) + j);
#pragma unroll
  for (int d = 0; d < 4; ++d)
#pragma unroll
    for (int j = 0; j < 4; ++j) {
      const int qrow = q0 + (lk << 2) + j;
      y[((size_t)(b * 1024 + qrow)) * 1024 + h * 64 + (d << 4) + lr] = f2bf(acc[d][j] * linv[j]);
    }
}

// ------------------------------ generic GEMM -------------------------------
// C[M,N] = A[M,K] (bf16, row-major) @ Bw[N,K]^T (bf16, row-major = weights)
// EPI: 0 store f32 (split-K partial plane z), 2 relu^2 -> bf16, 3 softcap f32
// NJ: fragments per wave along N; tile is 128 x (NJ*32). BK=32.
//
// Depth-3 pipeline over 4 LDS buffers (T4 counted-vmcnt schedule):
//   prologue: stage tiles 0,1,2 into bufs 0,1,2     (3*LPS loads in flight)
//   iter t:   s_waitcnt vmcnt(2*LPS)   -> tile t's loads landed (per-wave)
//             s_barrier                -> landed for ALL waves
//             stage tile t+3 -> buf[(t+3)&3]        (issued at TOP: ~3 steps
//                                                    of latency cover)
//             ds_read buf[t&3]; MFMA   (lgkmcnt forced by MFMA operand use)
//   Safety: buf[(t+3)&3] == buf[(t-1)&3]; its readers finished before the
//   barrier at top of t (their MFMAs waited lgkmcnt). A fast wave's next
//   stage sits behind the next barrier -> no skew hazard. Tail stages clamp
//   to the last valid tile (L2-warm dummy) keeping vmcnt counts uniform.
//   vmcnt(0) drain after the loop (LDS dealloc safety).
// Operand-swapped MFMA: D = mfma(B_frag, A_frag) computes the C^T tile ->
// each thread's 4-reg quad spans 4 CONSECUTIVE N columns -> float4 stores.
// XCD swizzle (T1): bijective chunked remap when nwg%8==0.

template <int EPI, int NJ>
__global__ __launch_bounds__(256)
void gemm_bf16(const unsigned short* __restrict__ A,
               const unsigned short* __restrict__ Bw,
               const float* __restrict__ Cin, void* __restrict__ Cout,
               int M, int N, int K, int kchunk) {
  constexpr int BN = NJ * 32;
  __shared__ unsigned short sA[4][128 * 32];
  __shared__ unsigned short sB[4][BN * 32];
  const int tid = threadIdx.x;

  int flat = blockIdx.x + gridDim.x * blockIdx.y;
  const int nwg = gridDim.x * gridDim.y;
  if ((nwg & 7) == 0) flat = (flat & 7) * (nwg >> 3) + (flat >> 3);
  const int m0 = (flat % gridDim.x) << 7;
  const int n0 = (flat / gridDim.x) * BN;
  const int k_begin = blockIdx.z * kchunk;
  int k_end = k_begin + kchunk; if (k_end > K) k_end = K;
  const int nsteps = (k_end - k_begin) >> 5;   // always >= 3 in this model

  const int wid = tid >> 6, lane = tid & 63;
  const int wr = wid >> 1, wc = wid & 1;
  const int lr = lane & 15, lk = lane >> 4;

  // staging geometry: thread tid covers row=tid>>2 (0..63), ch=(tid&3)*8
  const int row0 = tid >> 2, ch0 = (tid & 3) << 3;
  const unsigned short* gA0 = A + (size_t)(m0 + row0) * K + ch0;
  const unsigned short* gA1 = gA0 + (size_t)64 * K;
  const unsigned short* gB0 = Bw + (size_t)(n0 + row0) * K + ch0;
  const unsigned short* gB1 = gB0 + (size_t)64 * K;
  const int lofs = wid << 9;              // wave-uniform LDS base (shorts)

  auto stage = [&](int buf, int k0) {
    gload16(gA0 + k0, sA[buf] + lofs);
    gload16(gA1 + k0, sA[buf] + lofs + 2048);
    gload16(gB0 + k0, sB[buf] + lofs);
    if constexpr (NJ == 4) gload16(gB1 + k0, sB[buf] + lofs + 2048);
  };

  // prologue: 3 tiles in flight
  stage(0, k_begin);
  stage(1, k_begin + 32);
  stage(2, k_begin + 64);

  f32x4 acc[4][NJ] = {};
  for (int t = 0; t < nsteps; ++t) {
    // wait until only 2 future tiles outstanding -> tile t fully landed
    if constexpr (NJ == 4) asm volatile("s_waitcnt vmcnt(8)" ::: "memory");
    else                   asm volatile("s_waitcnt vmcnt(6)" ::: "memory");
    __builtin_amdgcn_s_barrier();
    __builtin_amdgcn_sched_barrier(0);
    {
      int kt = k_begin + ((t + 3) << 5);
      if (kt >= k_end) kt = k_end - 32;   // L2-warm dummy keeps count uniform
      stage((t + 3) & 3, kt);
    }
    const unsigned short* bufA = sA[t & 3];
    const unsigned short* bufB = sB[t & 3];
    bf16x8 af[4], bfr[NJ];
#pragma unroll
    for (int i = 0; i < 4; ++i)
      af[i] = *reinterpret_cast<const bf16x8*>(bufA + ((wr << 6) + (i << 4) + lr) * 32 + (lk << 3));
#pragma unroll
    for (int j = 0; j < NJ; ++j)
      bfr[j] = *reinterpret_cast<const bf16x8*>(bufB + (wc * (BN / 2) + (j << 4) + lr) * 32 + (lk << 3));
#pragma unroll
    for (int i = 0; i < 4; ++i)
#pragma unroll
      for (int j = 0; j < NJ; ++j)
        acc[i][j] = __builtin_amdgcn_mfma_f32_16x16x32_bf16(bfr[j], af[i], acc[i][j], 0, 0, 0);
  }
  asm volatile("s_waitcnt vmcnt(0)" ::: "memory");  // drain before LDS dealloc

  // C^T fragment layout: acc[i][j] reg e -> C[m][n], m = mbase + i*16,
  // n = nbase + j*16 + e (4 consecutive N cols per reg quad).
  const int mbase = m0 + (wr << 6) + lr;
  const int nbase = n0 + wc * (BN / 2) + (lk << 2);
  float* outF = (float*)Cout + (size_t)blockIdx.z * M * N;   // partial plane
#pragma unroll
  for (int i = 0; i < 4; ++i)
#pragma unroll
    for (int j = 0; j < NJ; ++j) {
      const int m = mbase + (i << 4);
      const int n = nbase + (j << 4);
      const size_t off = (size_t)m * N + n;
      f32x4 v = acc[i][j];
      if (EPI == 0) {
        *reinterpret_cast<f32x4*>(outF + off) = v;
      } else if (EPI == 1) {
        const f32x4 c = *reinterpret_cast<const f32x4*>(Cin + off);
        *reinterpret_cast<f32x4*>((float*)Cout + off) = c + v;
      } else if (EPI == 2) {
        ushort4 u;
        float r0 = v[0] > 0.f ? v[0] : 0.f;
        float r1 = v[1] > 0.f ? v[1] : 0.f;
        float r2 = v[2] > 0.f ? v[2] : 0.f;
        float r3 = v[3] > 0.f ? v[3] : 0.f;
        u.x = f2bf(r0 * r0); u.y = f2bf(r1 * r1);
        u.z = f2bf(r2 * r2); u.w = f2bf(r3 * r3);
        *reinterpret_cast<ushort4*>((unsigned short*)Cout + off) = u;
      } else {
        // 15*tanh(v/15) = 15 - 30/(exp(2v/15)+1); saturates correctly
        f32x4 o;
#pragma unroll
        for (int e = 0; e < 4; ++e) {
          const float ex = __expf(v[e] * (2.f / 15.f));
          o[e] = 15.f - 30.f / (ex + 1.f);
        }
        *reinterpret_cast<f32x4*>((float*)Cout + off) = o;
      }
    }
}

// ------------------------------- launcher ----------------------------------

extern "C" void kernel_launch(void* const* d_in, const int* in_sizes, int n_in,
                              void* d_out, int out_size, void* d_ws, size_t ws_size,
                              hipStream_t stream) {
  (void)in_sizes; (void)n_in; (void)out_size; (void)ws_size;
  const int*   ids  = (const int*)  d_in[0];
  const float* wte  = (const float*)d_in[1];
  const float* Wq   = (const float*)d_in[2];
  const float* Wk   = (const float*)d_in[3];
  const float* Wv   = (const float*)d_in[4];
  const float* Wo   = (const float*)d_in[5];
  const float* Wfc  = (const float*)d_in[6];
  const float* Wmp  = (const float*)d_in[7];
  const float* VeT  = (const float*)d_in[8];
  const float* VeG  = (const float*)d_in[9];
  const float* LmW  = (const float*)d_in[10];
  const float* ResC = (const float*)d_in[11];
  const float* X0C  = (const float*)d_in[12];
  const float* SmW  = (const float*)d_in[13];
  const float* SmL  = (const float*)d_in[14];

  char* p = (char*)d_ws;
  auto alloc = [&](size_t bytes) -> char* {
    char* r = p; p += (bytes + 255) & ~(size_t)255; return r;
  };
  float* x  = (float*)alloc((size_t)2048 * 1024 * 4);
  float* x0 = (float*)alloc((size_t)2048 * 1024 * 4);
  unsigned short* xn = (unsigned short*)alloc((size_t)2048 * 1024 * 2);
  unsigned short* hidden = (unsigned short*)alloc((size_t)2048 * 4096 * 2);
  float* qkvp = (float*)alloc((size_t)2 * 2048 * 1536 * 4);   // qkv split-K partials
  float* wop  = (float*)alloc((size_t)2 * 2048 * 1024 * 4);   // Wo split-K partials
  float* mpp  = (float*)alloc((size_t)4 * 2048 * 1024 * 4);   // MP split-K partials
  unsigned short* qbuf = (unsigned short*)alloc((size_t)2048 * 1024 * 2);
  unsigned short* kbuf = (unsigned short*)alloc((size_t)2048 * 256 * 2);
  unsigned short* vbuf = (unsigned short*)alloc((size_t)2048 * 256 * 2);
  unsigned short* vtb  = (unsigned short*)alloc((size_t)2048 * 256 * 2);
  unsigned short* ybuf = (unsigned short*)alloc((size_t)2048 * 1024 * 2);
  float* cost = (float*)alloc((size_t)1024 * 32 * 4);
  float* sint = (float*)alloc((size_t)1024 * 32 * 4);
  unsigned short* wqkv = (unsigned short*)alloc((size_t)6 * 1536 * 1024 * 2);
  unsigned short* wo   = (unsigned short*)alloc((size_t)6 * 1024 * 1024 * 2);
  unsigned short* wfc  = (unsigned short*)alloc((size_t)6 * 4096 * 1024 * 2);
  unsigned short* wmp  = (unsigned short*)alloc((size_t)6 * 1024 * 4096 * 2);
  unsigned short* wlm  = (unsigned short*)alloc((size_t)32000 * 1024 * 2);

  qkvw_pack_kernel<<<4608, 256, 0, stream>>>(Wq, Wk, Wv, wqkv);
  cvt_bf16_kernel<<<3072, 256, 0, stream>>>(Wo, wo, (long)6 * 1024 * 1024);
  cvt_bf16_kernel<<<12288, 256, 0, stream>>>(Wfc, wfc, (long)6 * 4096 * 1024);
  cvt_bf16_kernel<<<12288, 256, 0, stream>>>(Wmp, wmp, (long)6 * 1024 * 4096);
  cvt_bf16_kernel<<<16000, 256, 0, stream>>>(LmW, wlm, (long)32000 * 1024);
  rope_tab_kernel<<<128, 256, 0, stream>>>(cost, sint);
  embed_kernel<<<512, 256, 0, stream>>>(ids, wte, SmW, SmL, x, x0);

  static const int WIN[6] = {256, 1024, 256, 1024, 256, 1024};
  for (int l = 0; l < 6; ++l) {
    // layer-start combine; layers >0 also fold in previous layer's MP partials
    rmsnorm_kernel<<<512, 256, 0, stream>>>(x, x0, mpp, l == 0 ? 0 : 4,
                                            ResC, X0C, l, 1, xn);
    // QKV: split-K x2 -> two partial planes (summed inside qkv_post)
    gemm_bf16<0, 2><<<dim3(16, 24, 2), 256, 0, stream>>>(xn, wqkv + (size_t)l * 1536 * 1024,
                                                         nullptr, qkvp, 2048, 1536, 1024, 512);
    const float* vtab = nullptr; const float* vgw = nullptr;
    if (l == 1 || l == 3 || l == 5) {
      const int vi = (l - 1) / 2;
      vtab = VeT + (size_t)vi * 32000 * 256;
      vgw  = VeG + vi * 48;
    }
    qkv_post_kernel<<<512, 256, 0, stream>>>(qkvp, qkvp + (size_t)2048 * 1536, xn, ids,
                                             vtab, vgw, cost, sint, qbuf, kbuf, vbuf);
    vtrans_kernel<<<dim3(16, 8), 256, 0, stream>>>(vbuf, vtb);
    attn_kernel<<<dim3(64, 16, 2), 64, 0, stream>>>(qbuf, kbuf, vtb, ybuf, WIN[l]);
    // Wo: split-K x2 -> partials (reduced + added to x by next rmsnorm)
    gemm_bf16<0, 2><<<dim3(16, 16, 2), 256, 0, stream>>>(ybuf, wo + (size_t)l * 1024 * 1024,
                                                         nullptr, wop, 2048, 1024, 1024, 512);
    rmsnorm_kernel<<<512, 256, 0, stream>>>(x, x0, wop, 2, ResC, X0C, l, 0, xn);
    gemm_bf16<2, 4><<<dim3(16, 32), 256, 0, stream>>>(xn, wfc + (size_t)l * 4096 * 1024,
                                                      nullptr, hidden, 2048, 4096, 1024, 1024);
    // MP: split-K x4 (K=4096) -> partials (reduced by next layer's rmsnorm)
    gemm_bf16<0, 2><<<dim3(16, 16, 4), 256, 0, stream>>>(hidden, wmp + (size_t)l * 1024 * 4096,
                                                         nullptr, mpp, 2048, 1024, 4096, 1024);
  }
  rmsnorm_kernel<<<512, 256, 0, stream>>>(x, x0, mpp, 4, ResC, X0C, 0, 0, xn);
  gemm_bf16<3, 4><<<dim3(16, 250), 256, 0, stream>>>(xn, wlm, nullptr, (float*)d_out,
                                                     2048, 32000, 1024, 1024);
}

// Round 7
// 1442.811 us; speedup vs baseline: 1.1204x; 1.1204x over previous
//
#include <hip/hip_runtime.h>
#include <stdint.h>
#include <math.h>

// ---------------------------------------------------------------------------
// NanochatMiniLM forward on MI355X. Round 7: GEMM = R5's 2-buffer footprint
// (32/24 KB LDS -> occupancy preserved; R6's 4-buffer 64KB cost 30->22% occ)
// + R6's counted-vmcnt semantics (never drain vmcnt in the K-loop):
//   stage(t+1); s_waitcnt vmcnt(LPS) [tile t only]; s_barrier; ds_read+MFMA;
//   s_barrier.  Tile t+1's loads stay in flight across the entire iteration.
// Split-K partial planes + fused reduction (R4), C^T epilogue, fast softcap,
// XCD swizzle retained.
// B=2 T=1024 D=1024 H=16 KV=4 HD=64 L=6 VP=32000, windows {256,1024,...}
// ---------------------------------------------------------------------------

using bf16x8 = __attribute__((ext_vector_type(8))) short;   // 8 bf16 (4 VGPRs)
using f32x4  = __attribute__((ext_vector_type(4))) float;   // 4 f32 acc

#define DEV static __device__ __forceinline__

DEV unsigned short f2bf(float f) {            // RNE f32 -> bf16 bits
  unsigned int x = __builtin_bit_cast(unsigned int, f);
  x += 0x7fffu + ((x >> 16) & 1u);
  return (unsigned short)(x >> 16);
}
DEV float bf2f(unsigned short u) {
  return __builtin_bit_cast(float, (unsigned int)u << 16);
}
DEV unsigned int packbf2(float a, float b) {
  return (unsigned int)f2bf(a) | ((unsigned int)f2bf(b) << 16);
}

// async global->LDS, 16B per lane; LDS dest is wave-uniform base + lane*16
DEV void gload16(const unsigned short* g, unsigned short* l) {
  __builtin_amdgcn_global_load_lds(
      (__attribute__((address_space(1))) void*)const_cast<unsigned short*>(g),
      (__attribute__((address_space(3))) void*)l, 16, 0, 0);
}

// ---------------------------- weight conversion ----------------------------

extern "C" __global__ __launch_bounds__(256)
void cvt_bf16_kernel(const float* __restrict__ src, unsigned short* __restrict__ dst, long n) {
  long i = ((long)blockIdx.x * 256 + threadIdx.x) * 8;
  if (i >= n) return;
  const float4 a = *reinterpret_cast<const float4*>(src + i);
  const float4 b = *reinterpret_cast<const float4*>(src + i + 4);
  uint4 u;
  u.x = packbf2(a.x, a.y); u.y = packbf2(a.z, a.w);
  u.z = packbf2(b.x, b.y); u.w = packbf2(b.z, b.w);
  *reinterpret_cast<uint4*>(dst + i) = u;
}

// pack Wq|Wk|Wv (per layer) into contiguous [1536][1024] bf16 rows
extern "C" __global__ __launch_bounds__(256)
void qkvw_pack_kernel(const float* __restrict__ Wq, const float* __restrict__ Wk,
                      const float* __restrict__ Wv, unsigned short* __restrict__ dst) {
  long i = ((long)blockIdx.x * 256 + threadIdx.x) * 8;
  if (i >= (long)6 * 1536 * 1024) return;
  int c = (int)(i & 1023);
  int row = (int)(i >> 10);
  int l = row / 1536, r = row - l * 1536;
  const float* src;
  if (r < 1024)      src = Wq + ((size_t)l * 1024 + r) * 1024 + c;
  else if (r < 1280) src = Wk + ((size_t)l * 256 + (r - 1024)) * 1024 + c;
  else               src = Wv + ((size_t)l * 256 + (r - 1280)) * 1024 + c;
  const float4 a = *reinterpret_cast<const float4*>(src);
  const float4 b = *reinterpret_cast<const float4*>(src + 4);
  uint4 u;
  u.x = packbf2(a.x, a.y); u.y = packbf2(a.z, a.w);
  u.z = packbf2(b.x, b.y); u.w = packbf2(b.z, b.w);
  *reinterpret_cast<uint4*>(dst + i) = u;
}

// ------------------------------- rope tables -------------------------------

extern "C" __global__ __launch_bounds__(256)
void rope_tab_kernel(float* __restrict__ cost, float* __restrict__ sint) {
  const int idx = blockIdx.x * 256 + threadIdx.x;   // t*32 + i, 32768 total
  const int t = idx >> 5, i = idx & 31;
  const double inv = exp(((double)i * (-1.0 / 32.0)) * log(100000.0));
  const double f = (double)t * inv;
  cost[idx] = (float)cos(f);
  sint[idx] = (float)sin(f);
}

// ------------------------- embedding + rms + smear -------------------------
// one wave per token; lane owns channels c = i*256 + lane*4 (i=0..3)

extern "C" __global__ __launch_bounds__(256)
void embed_kernel(const int* __restrict__ ids, const float* __restrict__ wte,
                  const float* __restrict__ smear_w, const float* __restrict__ smear_l,
                  float* __restrict__ x, float* __restrict__ x0) {
  const int wid = threadIdx.x >> 6, lane = threadIdx.x & 63;
  const int tok = blockIdx.x * 4 + wid;
  const int t = tok & 1023;
  const float eps = 1.1920929e-7f;

  const float* wrow = wte + (size_t)ids[tok] * 1024;
  float4 v[4];
  float ss = 0.f;
#pragma unroll
  for (int i = 0; i < 4; ++i) {
    v[i] = *reinterpret_cast<const float4*>(wrow + i * 256 + lane * 4);
    ss += v[i].x * v[i].x + v[i].y * v[i].y + v[i].z * v[i].z + v[i].w * v[i].w;
  }
#pragma unroll
  for (int m = 1; m < 64; m <<= 1) ss += __shfl_xor(ss, m);
  const float sc = 1.f / sqrtf(ss * (1.f / 1024.f) + eps);

  float4 pv[4];
#pragma unroll
  for (int i = 0; i < 4; ++i) { pv[i].x = 0.f; pv[i].y = 0.f; pv[i].z = 0.f; pv[i].w = 0.f; }
  float scp = 0.f, gate = 0.f;
  if (t > 0) {
    const float* prow = wte + (size_t)ids[tok - 1] * 1024;
    float ssp = 0.f;
#pragma unroll
    for (int i = 0; i < 4; ++i) {
      pv[i] = *reinterpret_cast<const float4*>(prow + i * 256 + lane * 4);
      ssp += pv[i].x * pv[i].x + pv[i].y * pv[i].y + pv[i].z * pv[i].z + pv[i].w * pv[i].w;
    }
#pragma unroll
    for (int m = 1; m < 64; m <<= 1) ssp += __shfl_xor(ssp, m);
    scp = 1.f / sqrtf(ssp * (1.f / 1024.f) + eps);
    // gate from own rms'd channels 0..23 (v[0] holds c = lane*4..lane*4+3)
    float gp = 0.f;
    if (lane < 6) {
      gp = v[0].x * smear_w[lane * 4] + v[0].y * smear_w[lane * 4 + 1] +
           v[0].z * smear_w[lane * 4 + 2] + v[0].w * smear_w[lane * 4 + 3];
      gp *= sc;
    }
#pragma unroll
    for (int m = 1; m < 64; m <<= 1) gp += __shfl_xor(gp, m);
    gate = smear_l[0] / (1.f + __expf(-gp));
  }
#pragma unroll
  for (int i = 0; i < 4; ++i) {
    const int c = i * 256 + lane * 4;
    float4 o;
    o.x = v[i].x * sc + gate * pv[i].x * scp;
    o.y = v[i].y * sc + gate * pv[i].y * scp;
    o.z = v[i].z * sc + gate * pv[i].z * scp;
    o.w = v[i].w * sc + gate * pv[i].w * scp;
    *reinterpret_cast<float4*>(x + (size_t)tok * 1024 + c) = o;
    *reinterpret_cast<float4*>(x0 + (size_t)tok * 1024 + c) = o;
  }
}

// ------------- residual mix + split-K partial reduce + rmsnorm -------------
// x <- a*(x + sum_{p<np} parts[p]) + b*x0   (a=1,b=0 when combine==0)
// writes x back when it changed; xn <- rms(x) in bf16.
// parts: np contiguous [2048][1024] f32 planes (plane stride 2048*1024).

extern "C" __global__ __launch_bounds__(256)
void rmsnorm_kernel(float* __restrict__ x, const float* __restrict__ x0,
                    const float* __restrict__ parts, int np,
                    const float* __restrict__ residc, const float* __restrict__ x0c,
                    int layer, int combine, unsigned short* __restrict__ xn) {
  const int wid = threadIdx.x >> 6, lane = threadIdx.x & 63;
  const int tok = blockIdx.x * 4 + wid;
  float* xr = x + (size_t)tok * 1024;
  const float* x0r = x0 + (size_t)tok * 1024;
  float a = 1.f, bb = 0.f;
  if (combine) { a = residc[layer]; bb = x0c[layer]; }
  float4 v[4];
  float ss = 0.f;
#pragma unroll
  for (int i = 0; i < 4; ++i) {
    const int c = i * 256 + lane * 4;
    float4 xv = *reinterpret_cast<const float4*>(xr + c);
    for (int pi = 0; pi < np; ++pi) {
      const float4 pv = *reinterpret_cast<const float4*>(
          parts + (size_t)pi * 2048 * 1024 + (size_t)tok * 1024 + c);
      xv.x += pv.x; xv.y += pv.y; xv.z += pv.z; xv.w += pv.w;
    }
    if (combine) {
      const float4 ov = *reinterpret_cast<const float4*>(x0r + c);
      xv.x = a * xv.x + bb * ov.x; xv.y = a * xv.y + bb * ov.y;
      xv.z = a * xv.z + bb * ov.z; xv.w = a * xv.w + bb * ov.w;
    }
    if (combine || np > 0) *reinterpret_cast<float4*>(xr + c) = xv;
    v[i] = xv;
    ss += xv.x * xv.x + xv.y * xv.y + xv.z * xv.z + xv.w * xv.w;
  }
#pragma unroll
  for (int m = 1; m < 64; m <<= 1) ss += __shfl_xor(ss, m);
  const float sc = 1.f / sqrtf(ss * (1.f / 1024.f) + 1.1920929e-7f);
#pragma unroll
  for (int i = 0; i < 4; ++i) {
    const int c = i * 256 + lane * 4;
    ushort4 u;
    u.x = f2bf(v[i].x * sc); u.y = f2bf(v[i].y * sc);
    u.z = f2bf(v[i].z * sc); u.w = f2bf(v[i].w * sc);
    *reinterpret_cast<ushort4*>(xn + (size_t)tok * 1024 + c) = u;
  }
}

// ------------------- qkv post: rope + rms + ve-gate -> bf16 ----------------
// one wave per token; lane owns 16 contiguous channels (head = lane/4).
// qkv arrives as TWO split-K partial planes (qkv0 + qkv1), summed here.

extern "C" __global__ __launch_bounds__(256)
void qkv_post_kernel(const float* __restrict__ qkv0, const float* __restrict__ qkv1,
                     const unsigned short* __restrict__ xn,
                     const int* __restrict__ ids,
                     const float* __restrict__ ve_tab, const float* __restrict__ ve_gate_w,
                     const float* __restrict__ cost, const float* __restrict__ sint,
                     unsigned short* __restrict__ qb, unsigned short* __restrict__ kbuf,
                     unsigned short* __restrict__ vb) {
  const int wid = threadIdx.x >> 6, lane = threadIdx.x & 63;
  const int tok = blockIdx.x * 4 + wid;
  const int t = tok & 1023;
  const float eps = 1.1920929e-7f;
  const float* rowA = qkv0 + (size_t)tok * 1536;
  const float* rowB = qkv1 + (size_t)tok * 1536;
  const bool x1half = (lane & 2) == 0;   // lane%4 in {0,1}: x1; {2,3}: x2
  const int i0 = (lane & 1) << 4;        // rotary index base within half

  // ---- Q: 16 heads * 64, scale = 1.2/8 folded in ----
  {
    float v[16], p[16];
    {
      const float4* ra = reinterpret_cast<const float4*>(rowA + lane * 16);
      const float4* rb = reinterpret_cast<const float4*>(rowB + lane * 16);
#pragma unroll
      for (int i = 0; i < 4; ++i) {
        const float4 qa = ra[i], qb4 = rb[i];
        v[i * 4] = qa.x + qb4.x; v[i * 4 + 1] = qa.y + qb4.y;
        v[i * 4 + 2] = qa.z + qb4.z; v[i * 4 + 3] = qa.w + qb4.w;
      }
    }
#pragma unroll
    for (int i = 0; i < 16; ++i) p[i] = __shfl_xor(v[i], 2);
    float out[16]; float ssq = 0.f;
#pragma unroll
    for (int i = 0; i < 16; ++i) {
      const float c = cost[t * 32 + i0 + i];
      const float s = sint[t * 32 + i0 + i];
      out[i] = x1half ? (v[i] * c + p[i] * s) : (v[i] * c - p[i] * s);
      ssq += out[i] * out[i];
    }
    ssq += __shfl_xor(ssq, 1);
    ssq += __shfl_xor(ssq, 2);
    const float sc = 0.15f / sqrtf(ssq * (1.f / 64.f) + eps);
#pragma unroll
    for (int i = 0; i < 16; i += 4) {
      ushort4 u;
      u.x = f2bf(out[i] * sc); u.y = f2bf(out[i + 1] * sc);
      u.z = f2bf(out[i + 2] * sc); u.w = f2bf(out[i + 3] * sc);
      *reinterpret_cast<ushort4*>(qb + (size_t)tok * 1024 + lane * 16 + i) = u;
    }
  }
  const int kl = lane & 15;  // lanes 16-63 mirror 0-15 (keeps shfl uniform)
  // ---- K: 4 kv heads * 64, scale 1.2 ----
  {
    float v[16], p[16];
    {
      const float4* ra = reinterpret_cast<const float4*>(rowA + 1024 + kl * 16);
      const float4* rb = reinterpret_cast<const float4*>(rowB + 1024 + kl * 16);
#pragma unroll
      for (int i = 0; i < 4; ++i) {
        const float4 qa = ra[i], qb4 = rb[i];
        v[i * 4] = qa.x + qb4.x; v[i * 4 + 1] = qa.y + qb4.y;
        v[i * 4 + 2] = qa.z + qb4.z; v[i * 4 + 3] = qa.w + qb4.w;
      }
    }
#pragma unroll
    for (int i = 0; i < 16; ++i) p[i] = __shfl_xor(v[i], 2);
    float out[16]; float ssq = 0.f;
#pragma unroll
    for (int i = 0; i < 16; ++i) {
      const float c = cost[t * 32 + i0 + i];
      const float s = sint[t * 32 + i0 + i];
      out[i] = x1half ? (v[i] * c + p[i] * s) : (v[i] * c - p[i] * s);
      ssq += out[i] * out[i];
    }
    ssq += __shfl_xor(ssq, 1);
    ssq += __shfl_xor(ssq, 2);
    const float sc = 1.2f / sqrtf(ssq * (1.f / 64.f) + eps);
    if (lane < 16) {
#pragma unroll
      for (int i = 0; i < 16; i += 4) {
        ushort4 u;
        u.x = f2bf(out[i] * sc); u.y = f2bf(out[i + 1] * sc);
        u.z = f2bf(out[i + 2] * sc); u.w = f2bf(out[i + 3] * sc);
        *reinterpret_cast<ushort4*>(kbuf + (size_t)tok * 256 + kl * 16 + i) = u;
      }
    }
  }
  // ---- V: optional value-embedding gate ----
  {
    float v[16];
    {
      const float4* ra = reinterpret_cast<const float4*>(rowA + 1280 + kl * 16);
      const float4* rb = reinterpret_cast<const float4*>(rowB + 1280 + kl * 16);
#pragma unroll
      for (int i = 0; i < 4; ++i) {
        const float4 qa = ra[i], qb4 = rb[i];
        v[i * 4] = qa.x + qb4.x; v[i * 4 + 1] = qa.y + qb4.y;
        v[i * 4 + 2] = qa.z + qb4.z; v[i * 4 + 3] = qa.w + qb4.w;
      }
    }
    if (ve_tab != nullptr) {
      const int kvh = kl >> 2;
      float g = 0.f;
#pragma unroll
      for (int c = 0; c < 12; ++c)
        g += bf2f(xn[(size_t)tok * 1024 + c]) * ve_gate_w[kvh * 12 + c];
      g = 3.f / (1.f + __expf(-g));
      const float* ver = ve_tab + (size_t)ids[tok] * 256 + kl * 16;
#pragma unroll
      for (int i = 0; i < 16; ++i) v[i] += g * ver[i];
    }
    if (lane < 16) {
#pragma unroll
      for (int i = 0; i < 16; i += 4) {
        ushort4 u;
        u.x = f2bf(v[i]); u.y = f2bf(v[i + 1]); u.z = f2bf(v[i + 2]); u.w = f2bf(v[i + 3]);
        *reinterpret_cast<ushort4*>(vb + (size_t)tok * 256 + kl * 16 + i) = u;
      }
    }
  }
}

// ---------------- V transpose: vb[b][t][kv*64+d] -> vt[b*4+kv][d][t] -------

extern "C" __global__ __launch_bounds__(256)
void vtrans_kernel(const unsigned short* __restrict__ vb, unsigned short* __restrict__ vt) {
  __shared__ unsigned short tile[64][72];
  const int t0 = blockIdx.x << 6;
  const int bk = blockIdx.y;               // b*4 + kv
  const int tid = threadIdx.x;
  {
    const int r = tid >> 2, cs = (tid & 3) << 4;
    const unsigned short* src = vb + ((size_t)((bk >> 2) * 1024 + t0 + r)) * 256 + (bk & 3) * 64 + cs;
    *reinterpret_cast<uint4*>(&tile[r][cs]) = *reinterpret_cast<const uint4*>(src);
    *reinterpret_cast<uint4*>(&tile[r][cs + 8]) = *reinterpret_cast<const uint4*>(src + 8);
  }
  __syncthreads();
  {
    const int d = tid >> 2, ts = (tid & 3) << 4;
    unsigned int w[8];
#pragma unroll
    for (int i = 0; i < 8; ++i)
      w[i] = (unsigned int)tile[ts + 2 * i][d] | ((unsigned int)tile[ts + 2 * i + 1][d] << 16);
    unsigned short* dst = vt + ((size_t)bk * 64 + d) * 1024 + t0 + ts;
    uint4 u0; u0.x = w[0]; u0.y = w[1]; u0.z = w[2]; u0.w = w[3];
    uint4 u1; u1.x = w[4]; u1.y = w[5]; u1.z = w[6]; u1.w = w[7];
    *reinterpret_cast<uint4*>(dst) = u0;
    *reinterpret_cast<uint4*>(dst + 8) = u1;
  }
}

// --------------------------- flash attention -------------------------------
// 1 wave per (b, h, 16-query block). Swapped QK^T: St[key][query] via
// mfma(K, Q); softmax reduce over lane groups; P -> LDS -> PV A-operand;
// V^T rows give contiguous PV B-operand.

extern "C" __global__ __launch_bounds__(64)
void attn_kernel(const unsigned short* __restrict__ qb,
                 const unsigned short* __restrict__ kb,
                 const unsigned short* __restrict__ vt,
                 unsigned short* __restrict__ y, int W) {
  __shared__ unsigned short p_lds[16 * 32];
  const int lane = threadIdx.x;
  const int q0 = blockIdx.x << 4;
  const int h = blockIdx.y;
  const int b = blockIdx.z;
  const int kv = h >> 2;
  const int lr = lane & 15, lk = lane >> 4;

  bf16x8 qf0, qf1;
  {
    const unsigned short* qrow = qb + ((size_t)(b * 1024 + q0 + lr)) * 1024 + h * 64 + (lk << 3);
    qf0 = *reinterpret_cast<const bf16x8*>(qrow);
    qf1 = *reinterpret_cast<const bf16x8*>(qrow + 32);
  }
  f32x4 acc[4] = {};
  float m_run = -3e38f, l_run = 0.f;
  int kstart = q0 - W + 1; if (kstart < 0) kstart = 0;
  kstart &= ~31;
  const int qq = q0 + lr;

  for (int kb0 = kstart; kb0 < q0 + 16; kb0 += 32) {
    f32x4 st[2];
#pragma unroll
    for (int s = 0; s < 2; ++s) {
      const unsigned short* krow = kb + ((size_t)(b * 1024 + kb0 + (s << 4) + lr)) * 256 + kv * 64 + (lk << 3);
      bf16x8 kf0 = *reinterpret_cast<const bf16x8*>(krow);
      bf16x8 kf1 = *reinterpret_cast<const bf16x8*>(krow + 32);
      f32x4 z = {0.f, 0.f, 0.f, 0.f};
      z = __builtin_amdgcn_mfma_f32_16x16x32_bf16(kf0, qf0, z, 0, 0, 0);
      st[s] = __builtin_amdgcn_mfma_f32_16x16x32_bf16(kf1, qf1, z, 0, 0, 0);
    }
    float sv[8];
    float bm = -3e38f;
#pragma unroll
    for (int s = 0; s < 2; ++s)
#pragma unroll
      for (int j = 0; j < 4; ++j) {
        const int key = kb0 + (s << 4) + (lk << 2) + j;
        const bool valid = (key <= qq) && (qq - key < W);
        const float xx = valid ? st[s][j] : -3e38f;
        sv[s * 4 + j] = xx;
        bm = fmaxf(bm, xx);
      }
    bm = fmaxf(bm, __shfl_xor(bm, 16));
    bm = fmaxf(bm, __shfl_xor(bm, 32));
    const float m_new = fmaxf(m_run, bm);
    const float alpha = __expf(m_run - m_new);
    float psum = 0.f;
    unsigned short pbv[8];
#pragma unroll
    for (int s = 0; s < 2; ++s)
#pragma unroll
      for (int j = 0; j < 4; ++j) {
        const int key = kb0 + (s << 4) + (lk << 2) + j;
        const bool valid = (key <= qq) && (qq - key < W);
        const float pv = valid ? __expf(sv[s * 4 + j] - m_new) : 0.f;
        psum += pv;
        pbv[s * 4 + j] = f2bf(pv);
      }
    psum += __shfl_xor(psum, 16);
    psum += __shfl_xor(psum, 32);
    l_run = l_run * alpha + psum;
    m_run = m_new;

    __syncthreads();  // WAR vs previous iteration's reads
    {
      ushort4 u0, u1;
      u0.x = pbv[0]; u0.y = pbv[1]; u0.z = pbv[2]; u0.w = pbv[3];
      u1.x = pbv[4]; u1.y = pbv[5]; u1.z = pbv[6]; u1.w = pbv[7];
      *reinterpret_cast<ushort4*>(p_lds + lr * 32 + (lk << 2)) = u0;
      *reinterpret_cast<ushort4*>(p_lds + lr * 32 + 16 + (lk << 2)) = u1;
    }
    __syncthreads();
    const bf16x8 pf = *reinterpret_cast<const bf16x8*>(p_lds + lr * 32 + (lk << 3));
    float al[4];
#pragma unroll
    for (int j = 0; j < 4; ++j) al[j] = __shfl(alpha, (lk << 2) + j);
#pragma unroll
    for (int d = 0; d < 4; ++d) {
      const unsigned short* vrow = vt + ((size_t)((b * 4 + kv) * 64 + (d << 4) + lr)) * 1024 + kb0 + (lk << 3);
      const bf16x8 vf = *reinterpret_cast<const bf16x8*>(vrow);
#pragma unroll
      for (int j = 0; j < 4; ++j) acc[d][j] *= al[j];
      acc[d] = __builtin_amdgcn_mfma_f32_16x16x32_bf16(pf, vf, acc[d], 0, 0, 0);
    }
  }
  float linv[4];
#pragma unroll
  for (int j = 0; j < 4; ++j) linv[j] = 1.f / __shfl(l_run, (lk << 2) + j);
#pragma unroll
  for (int d = 0; d < 4; ++d)
#pragma unroll
    for (int j = 0; j < 4; ++j) {
      const int qrow = q0 + (lk << 2) + j;
      y[((size_t)(b * 1024 + qrow)) * 1024 + h * 64 + (d << 4) + lr] = f2bf(acc[d][j] * linv[j]);
    }
}

// ------------------------------ generic GEMM -------------------------------
// C[M,N] = A[M,K] (bf16, row-major) @ Bw[N,K]^T (bf16, row-major = weights)
// EPI: 0 store f32 (split-K partial plane z), 2 relu^2 -> bf16, 3 softcap f32
// NJ: fragments per wave along N; tile is 128 x (NJ*32). BK=32. 2 LDS bufs.
//
// Counted-vmcnt schedule (T4), 2-buffer footprint (occupancy preserved):
//   prologue: stage(buf0, tile0)                       [LPS in flight]
//   iter t:   stage(buf[(t+1)&1], tile t+1)            [2*LPS in flight]
//             s_waitcnt vmcnt(LPS)   -> tile t landed; t+1 stays in flight
//             s_barrier              -> landed for ALL waves
//             sched_barrier(0); ds_read buf[t&1]; MFMA
//             s_barrier              -> all waves' reads done
//   Safety: stage at t+1 targets buf[t&1]; its readers' ds_reads are
//   lgkmcnt-drained before their MFMAs (hence before their end-of-t barrier
//   arrival). DMA for t+1 targets the buffer last read at t-1, fenced by the
//   end-of-(t-1) barrier. vmcnt retires FIFO per wave. Tail: dummy stage
//   clamped to k_begin keeps counts uniform; vmcnt(0) drain before epilogue.
// Operand-swapped MFMA: D = mfma(B_frag, A_frag) computes the C^T tile ->
// each thread's 4-reg quad spans 4 CONSECUTIVE N columns -> float4 stores.
// XCD swizzle (T1): bijective chunked remap when nwg%8==0.

template <int EPI, int NJ>
__global__ __launch_bounds__(256)
void gemm_bf16(const unsigned short* __restrict__ A,
               const unsigned short* __restrict__ Bw,
               const float* __restrict__ Cin, void* __restrict__ Cout,
               int M, int N, int K, int kchunk) {
  constexpr int BN = NJ * 32;
  __shared__ unsigned short sA[2][128 * 32];
  __shared__ unsigned short sB[2][BN * 32];
  const int tid = threadIdx.x;

  int flat = blockIdx.x + gridDim.x * blockIdx.y;
  const int nwg = gridDim.x * gridDim.y;
  if ((nwg & 7) == 0) flat = (flat & 7) * (nwg >> 3) + (flat >> 3);
  const int m0 = (flat % gridDim.x) << 7;
  const int n0 = (flat / gridDim.x) * BN;
  const int k_begin = blockIdx.z * kchunk;
  int k_end = k_begin + kchunk; if (k_end > K) k_end = K;
  const int nsteps = (k_end - k_begin) >> 5;

  const int wid = tid >> 6, lane = tid & 63;
  const int wr = wid >> 1, wc = wid & 1;
  const int lr = lane & 15, lk = lane >> 4;

  // staging geometry: thread tid covers row=tid>>2 (0..63), ch=(tid&3)*8
  const int row0 = tid >> 2, ch0 = (tid & 3) << 3;
  const unsigned short* gA0 = A + (size_t)(m0 + row0) * K + ch0;
  const unsigned short* gA1 = gA0 + (size_t)64 * K;
  const unsigned short* gB0 = Bw + (size_t)(n0 + row0) * K + ch0;
  const unsigned short* gB1 = gB0 + (size_t)64 * K;
  const int lofs = wid << 9;              // wave-uniform LDS base (shorts)

  auto stage = [&](int buf, int k0) {
    gload16(gA0 + k0, sA[buf] + lofs);
    gload16(gA1 + k0, sA[buf] + lofs + 2048);
    gload16(gB0 + k0, sB[buf] + lofs);
    if constexpr (NJ == 4) gload16(gB1 + k0, sB[buf] + lofs + 2048);
  };

  stage(0, k_begin);                       // prologue: tile 0 in flight

  f32x4 acc[4][NJ] = {};
  for (int t = 0; t < nsteps; ++t) {
    // issue next tile's loads FIRST (they stay in flight this whole iter)
    int kt = k_begin + ((t + 1) << 5);
    if (kt >= k_end) kt = k_begin;         // L2-warm dummy keeps count uniform
    stage((t + 1) & 1, kt);
    // retire ONLY tile t's loads (LPS = loads per stage)
    if constexpr (NJ == 4) asm volatile("s_waitcnt vmcnt(4)" ::: "memory");
    else                   asm volatile("s_waitcnt vmcnt(3)" ::: "memory");
    __builtin_amdgcn_s_barrier();          // tile t visible to all waves
    __builtin_amdgcn_sched_barrier(0);
    const unsigned short* bufA = sA[t & 1];
    const unsigned short* bufB = sB[t & 1];
    bf16x8 af[4], bfr[NJ];
#pragma unroll
    for (int i = 0; i < 4; ++i)
      af[i] = *reinterpret_cast<const bf16x8*>(bufA + ((wr << 6) + (i << 4) + lr) * 32 + (lk << 3));
#pragma unroll
    for (int j = 0; j < NJ; ++j)
      bfr[j] = *reinterpret_cast<const bf16x8*>(bufB + (wc * (BN / 2) + (j << 4) + lr) * 32 + (lk << 3));
#pragma unroll
    for (int i = 0; i < 4; ++i)
#pragma unroll
      for (int j = 0; j < NJ; ++j)
        acc[i][j] = __builtin_amdgcn_mfma_f32_16x16x32_bf16(bfr[j], af[i], acc[i][j], 0, 0, 0);
    __builtin_amdgcn_s_barrier();          // all reads of buf[t&1] done
  }
  asm volatile("s_waitcnt vmcnt(0)" ::: "memory");  // drain before LDS reuse

  // C^T fragment layout: acc[i][j] reg e -> C[m][n], m = mbase + i*16,
  // n = nbase + j*16 + e (4 consecutive N cols per reg quad).
  const int mbase = m0 + (wr << 6) + lr;
  const int nbase = n0 + wc * (BN / 2) + (lk << 2);
  float* outF = (float*)Cout + (size_t)blockIdx.z * M * N;   // partial plane
#pragma unroll
  for (int i = 0; i < 4; ++i)
#pragma unroll
    for (int j = 0; j < NJ; ++j) {
      const int m = mbase + (i << 4);
      const int n = nbase + (j << 4);
      const size_t off = (size_t)m * N + n;
      f32x4 v = acc[i][j];
      if (EPI == 0) {
        *reinterpret_cast<f32x4*>(outF + off) = v;
      } else if (EPI == 1) {
        const f32x4 c = *reinterpret_cast<const f32x4*>(Cin + off);
        *reinterpret_cast<f32x4*>((float*)Cout + off) = c + v;
      } else if (EPI == 2) {
        ushort4 u;
        float r0 = v[0] > 0.f ? v[0] : 0.f;
        float r1 = v[1] > 0.f ? v[1] : 0.f;
        float r2 = v[2] > 0.f ? v[2] : 0.f;
        float r3 = v[3] > 0.f ? v[3] : 0.f;
        u.x = f2bf(r0 * r0); u.y = f2bf(r1 * r1);
        u.z = f2bf(r2 * r2); u.w = f2bf(r3 * r3);
        *reinterpret_cast<ushort4*>((unsigned short*)Cout + off) = u;
      } else {
        // 15*tanh(v/15) = 15 - 30/(exp(2v/15)+1); saturates correctly
        f32x4 o;
#pragma unroll
        for (int e = 0; e < 4; ++e) {
          const float ex = __expf(v[e] * (2.f / 15.f));
          o[e] = 15.f - 30.f / (ex + 1.f);
        }
        *reinterpret_cast<f32x4*>((float*)Cout + off) = o;
      }
    }
}

// ------------------------------- launcher ----------------------------------

extern "C" void kernel_launch(void* const* d_in, const int* in_sizes, int n_in,
                              void* d_out, int out_size, void* d_ws, size_t ws_size,
                              hipStream_t stream) {
  (void)in_sizes; (void)n_in; (void)out_size; (void)ws_size;
  const int*   ids  = (const int*)  d_in[0];
  const float* wte  = (const float*)d_in[1];
  const float* Wq   = (const float*)d_in[2];
  const float* Wk   = (const float*)d_in[3];
  const float* Wv   = (const float*)d_in[4];
  const float* Wo   = (const float*)d_in[5];
  const float* Wfc  = (const float*)d_in[6];
  const float* Wmp  = (const float*)d_in[7];
  const float* VeT  = (const float*)d_in[8];
  const float* VeG  = (const float*)d_in[9];
  const float* LmW  = (const float*)d_in[10];
  const float* ResC = (const float*)d_in[11];
  const float* X0C  = (const float*)d_in[12];
  const float* SmW  = (const float*)d_in[13];
  const float* SmL  = (const float*)d_in[14];

  char* p = (char*)d_ws;
  auto alloc = [&](size_t bytes) -> char* {
    char* r = p; p += (bytes + 255) & ~(size_t)255; return r;
  };
  float* x  = (float*)alloc((size_t)2048 * 1024 * 4);
  float* x0 = (float*)alloc((size_t)2048 * 1024 * 4);
  unsigned short* xn = (unsigned short*)alloc((size_t)2048 * 1024 * 2);
  unsigned short* hidden = (unsigned short*)alloc((size_t)2048 * 4096 * 2);
  float* qkvp = (float*)alloc((size_t)2 * 2048 * 1536 * 4);   // qkv split-K partials
  float* wop  = (float*)alloc((size_t)2 * 2048 * 1024 * 4);   // Wo split-K partials
  float* mpp  = (float*)alloc((size_t)4 * 2048 * 1024 * 4);   // MP split-K partials
  unsigned short* qbuf = (unsigned short*)alloc((size_t)2048 * 1024 * 2);
  unsigned short* kbuf = (unsigned short*)alloc((size_t)2048 * 256 * 2);
  unsigned short* vbuf = (unsigned short*)alloc((size_t)2048 * 256 * 2);
  unsigned short* vtb  = (unsigned short*)alloc((size_t)2048 * 256 * 2);
  unsigned short* ybuf = (unsigned short*)alloc((size_t)2048 * 1024 * 2);
  float* cost = (float*)alloc((size_t)1024 * 32 * 4);
  float* sint = (float*)alloc((size_t)1024 * 32 * 4);
  unsigned short* wqkv = (unsigned short*)alloc((size_t)6 * 1536 * 1024 * 2);
  unsigned short* wo   = (unsigned short*)alloc((size_t)6 * 1024 * 1024 * 2);
  unsigned short* wfc  = (unsigned short*)alloc((size_t)6 * 4096 * 1024 * 2);
  unsigned short* wmp  = (unsigned short*)alloc((size_t)6 * 1024 * 4096 * 2);
  unsigned short* wlm  = (unsigned short*)alloc((size_t)32000 * 1024 * 2);

  qkvw_pack_kernel<<<4608, 256, 0, stream>>>(Wq, Wk, Wv, wqkv);
  cvt_bf16_kernel<<<3072, 256, 0, stream>>>(Wo, wo, (long)6 * 1024 * 1024);
  cvt_bf16_kernel<<<12288, 256, 0, stream>>>(Wfc, wfc, (long)6 * 4096 * 1024);
  cvt_bf16_kernel<<<12288, 256, 0, stream>>>(Wmp, wmp, (long)6 * 1024 * 4096);
  cvt_bf16_kernel<<<16000, 256, 0, stream>>>(LmW, wlm, (long)32000 * 1024);
  rope_tab_kernel<<<128, 256, 0, stream>>>(cost, sint);
  embed_kernel<<<512, 256, 0, stream>>>(ids, wte, SmW, SmL, x, x0);

  static const int WIN[6] = {256, 1024, 256, 1024, 256, 1024};
  for (int l = 0; l < 6; ++l) {
    // layer-start combine; layers >0 also fold in previous layer's MP partials
    rmsnorm_kernel<<<512, 256, 0, stream>>>(x, x0, mpp, l == 0 ? 0 : 4,
                                            ResC, X0C, l, 1, xn);
    // QKV: split-K x2 -> two partial planes (summed inside qkv_post)
    gemm_bf16<0, 2><<<dim3(16, 24, 2), 256, 0, stream>>>(xn, wqkv + (size_t)l * 1536 * 1024,
                                                         nullptr, qkvp, 2048, 1536, 1024, 512);
    const float* vtab = nullptr; const float* vgw = nullptr;
    if (l == 1 || l == 3 || l == 5) {
      const int vi = (l - 1) / 2;
      vtab = VeT + (size_t)vi * 32000 * 256;
      vgw  = VeG + vi * 48;
    }
    qkv_post_kernel<<<512, 256, 0, stream>>>(qkvp, qkvp + (size_t)2048 * 1536, xn, ids,
                                             vtab, vgw, cost, sint, qbuf, kbuf, vbuf);
    vtrans_kernel<<<dim3(16, 8), 256, 0, stream>>>(vbuf, vtb);
    attn_kernel<<<dim3(64, 16, 2), 64, 0, stream>>>(qbuf, kbuf, vtb, ybuf, WIN[l]);
    // Wo: split-K x2 -> partials (reduced + added to x by next rmsnorm)
    gemm_bf16<0, 2><<<dim3(16, 16, 2), 256, 0, stream>>>(ybuf, wo + (size_t)l * 1024 * 1024,
                                                         nullptr, wop, 2048, 1024, 1024, 512);
    rmsnorm_kernel<<<512, 256, 0, stream>>>(x, x0, wop, 2, ResC, X0C, l, 0, xn);
    gemm_bf16<2, 4><<<dim3(16, 32), 256, 0, stream>>>(xn, wfc + (size_t)l * 4096 * 1024,
                                                      nullptr, hidden, 2048, 4096, 1024, 1024);
    // MP: split-K x4 (K=4096) -> partials (reduced by next layer's rmsnorm)
    gemm_bf16<0, 2><<<dim3(16, 16, 4), 256, 0, stream>>>(hidden, wmp + (size_t)l * 1024 * 4096,
                                                         nullptr, mpp, 2048, 1024, 4096, 1024);
  }
  rmsnorm_kernel<<<512, 256, 0, stream>>>(x, x0, mpp, 4, ResC, X0C, 0, 0, xn);
  gemm_bf16<3, 4><<<dim3(16, 250), 256, 0, stream>>>(xn, wlm, nullptr, (float*)d_out,
                                                     2048, 32000, 1024, 1024);
}

// Round 8
// 1391.279 us; speedup vs baseline: 1.1619x; 1.0370x over previous
//
#include <hip/hip_runtime.h>
#include <stdint.h>
#include <math.h>

// ---------------------------------------------------------------------------
// NanochatMiniLM forward on MI355X. Round 8: GEMM core reverted to R5's
// proven best (2-buffer dbuf, stage(t+1) issued before MFMA cluster, ONE
// __syncthreads per K-step; R6 depth-3 killed occupancy, R7 counted-vmcnt
// needed 2 barriers and lost). New: l=0 rmsnorm fused into embed (x==x0
// there), 5 prologue conversion kernels merged into one.
// Split-K partial planes + fused reduction, C^T epilogue, fast softcap,
// XCD swizzle retained.
// B=2 T=1024 D=1024 H=16 KV=4 HD=64 L=6 VP=32000, windows {256,1024,...}
// ---------------------------------------------------------------------------

using bf16x8 = __attribute__((ext_vector_type(8))) short;   // 8 bf16 (4 VGPRs)
using f32x4  = __attribute__((ext_vector_type(4))) float;   // 4 f32 acc

#define DEV static __device__ __forceinline__

DEV unsigned short f2bf(float f) {            // RNE f32 -> bf16 bits
  unsigned int x = __builtin_bit_cast(unsigned int, f);
  x += 0x7fffu + ((x >> 16) & 1u);
  return (unsigned short)(x >> 16);
}
DEV float bf2f(unsigned short u) {
  return __builtin_bit_cast(float, (unsigned int)u << 16);
}
DEV unsigned int packbf2(float a, float b) {
  return (unsigned int)f2bf(a) | ((unsigned int)f2bf(b) << 16);
}

// async global->LDS, 16B per lane; LDS dest is wave-uniform base + lane*16
DEV void gload16(const unsigned short* g, unsigned short* l) {
  __builtin_amdgcn_global_load_lds(
      (__attribute__((address_space(1))) void*)const_cast<unsigned short*>(g),
      (__attribute__((address_space(3))) void*)l, 16, 0, 0);
}

// ------------------- merged weight conversion (one launch) -----------------
// Segments (in 8-element vectors):
//   [0,S0)   : wqkv pack  (6*1536*1024)
//   [S0,S1)  : wo         (6*1024*1024)
//   [S1,S2)  : wfc        (6*4096*1024)
//   [S2,S3)  : wmp        (6*1024*4096)
//   [S3,S4)  : wlm        (32000*1024)

extern "C" __global__ __launch_bounds__(256)
void prep_weights_kernel(const float* __restrict__ Wq, const float* __restrict__ Wk,
                         const float* __restrict__ Wv, const float* __restrict__ Wo,
                         const float* __restrict__ Wfc, const float* __restrict__ Wmp,
                         const float* __restrict__ LmW,
                         unsigned short* __restrict__ wqkv, unsigned short* __restrict__ wo,
                         unsigned short* __restrict__ wfc, unsigned short* __restrict__ wmp,
                         unsigned short* __restrict__ wlm) {
  const long v = (long)blockIdx.x * 256 + threadIdx.x;   // vector index
  const long S0 = 1179648, S1 = S0 + 786432, S2 = S1 + 3145728,
             S3 = S2 + 3145728, S4 = S3 + 4096000;
  const float* src; unsigned short* dst;
  if (v < S0) {
    const long i = v * 8;
    const int c = (int)(i & 1023);
    const int row = (int)(i >> 10);
    const int l = row / 1536, r = row - l * 1536;
    if (r < 1024)      src = Wq + ((size_t)l * 1024 + r) * 1024 + c;
    else if (r < 1280) src = Wk + ((size_t)l * 256 + (r - 1024)) * 1024 + c;
    else               src = Wv + ((size_t)l * 256 + (r - 1280)) * 1024 + c;
    dst = wqkv + i;
  } else if (v < S1) {
    const long i = (v - S0) * 8; src = Wo + i;  dst = wo + i;
  } else if (v < S2) {
    const long i = (v - S1) * 8; src = Wfc + i; dst = wfc + i;
  } else if (v < S3) {
    const long i = (v - S2) * 8; src = Wmp + i; dst = wmp + i;
  } else if (v < S4) {
    const long i = (v - S3) * 8; src = LmW + i; dst = wlm + i;
  } else {
    return;
  }
  const float4 a = *reinterpret_cast<const float4*>(src);
  const float4 b = *reinterpret_cast<const float4*>(src + 4);
  uint4 u;
  u.x = packbf2(a.x, a.y); u.y = packbf2(a.z, a.w);
  u.z = packbf2(b.x, b.y); u.w = packbf2(b.z, b.w);
  *reinterpret_cast<uint4*>(dst) = u;
}

// ------------------------------- rope tables -------------------------------

extern "C" __global__ __launch_bounds__(256)
void rope_tab_kernel(float* __restrict__ cost, float* __restrict__ sint) {
  const int idx = blockIdx.x * 256 + threadIdx.x;   // t*32 + i, 32768 total
  const int t = idx >> 5, i = idx & 31;
  const double inv = exp(((double)i * (-1.0 / 32.0)) * log(100000.0));
  const double f = (double)t * inv;
  cost[idx] = (float)cos(f);
  sint[idx] = (float)sin(f);
}

// ------------- embedding + rms + smear + fused l=0 combine+rms -------------
// one wave per token; lane owns channels c = i*256 + lane*4 (i=0..3).
// At layer 0, x == x0, so the reference's  x = a*x + b*x0  is  a*o + b*o
// elementwise (same FP ordering as the old rmsnorm kernel); we emit
// x0 = o,  x = a*o+b*o,  xn = bf16(rms(x))  -- saving the l=0 rmsnorm pass.

extern "C" __global__ __launch_bounds__(256)
void embed_kernel(const int* __restrict__ ids, const float* __restrict__ wte,
                  const float* __restrict__ smear_w, const float* __restrict__ smear_l,
                  const float* __restrict__ residc, const float* __restrict__ x0c,
                  float* __restrict__ x, float* __restrict__ x0,
                  unsigned short* __restrict__ xn) {
  const int wid = threadIdx.x >> 6, lane = threadIdx.x & 63;
  const int tok = blockIdx.x * 4 + wid;
  const int t = tok & 1023;
  const float eps = 1.1920929e-7f;

  const float* wrow = wte + (size_t)ids[tok] * 1024;
  float4 v[4];
  float ss = 0.f;
#pragma unroll
  for (int i = 0; i < 4; ++i) {
    v[i] = *reinterpret_cast<const float4*>(wrow + i * 256 + lane * 4);
    ss += v[i].x * v[i].x + v[i].y * v[i].y + v[i].z * v[i].z + v[i].w * v[i].w;
  }
#pragma unroll
  for (int m = 1; m < 64; m <<= 1) ss += __shfl_xor(ss, m);
  const float sc = 1.f / sqrtf(ss * (1.f / 1024.f) + eps);

  float4 pv[4];
#pragma unroll
  for (int i = 0; i < 4; ++i) { pv[i].x = 0.f; pv[i].y = 0.f; pv[i].z = 0.f; pv[i].w = 0.f; }
  float scp = 0.f, gate = 0.f;
  if (t > 0) {
    const float* prow = wte + (size_t)ids[tok - 1] * 1024;
    float ssp = 0.f;
#pragma unroll
    for (int i = 0; i < 4; ++i) {
      pv[i] = *reinterpret_cast<const float4*>(prow + i * 256 + lane * 4);
      ssp += pv[i].x * pv[i].x + pv[i].y * pv[i].y + pv[i].z * pv[i].z + pv[i].w * pv[i].w;
    }
#pragma unroll
    for (int m = 1; m < 64; m <<= 1) ssp += __shfl_xor(ssp, m);
    scp = 1.f / sqrtf(ssp * (1.f / 1024.f) + eps);
    // gate from own rms'd channels 0..23 (v[0] holds c = lane*4..lane*4+3)
    float gp = 0.f;
    if (lane < 6) {
      gp = v[0].x * smear_w[lane * 4] + v[0].y * smear_w[lane * 4 + 1] +
           v[0].z * smear_w[lane * 4 + 2] + v[0].w * smear_w[lane * 4 + 3];
      gp *= sc;
    }
#pragma unroll
    for (int m = 1; m < 64; m <<= 1) gp += __shfl_xor(gp, m);
    gate = smear_l[0] / (1.f + __expf(-gp));
  }
  const float a0 = residc[0], b0 = x0c[0];
  float4 y[4];
  float ssy = 0.f;
#pragma unroll
  for (int i = 0; i < 4; ++i) {
    const int c = i * 256 + lane * 4;
    float4 o;
    o.x = v[i].x * sc + gate * pv[i].x * scp;
    o.y = v[i].y * sc + gate * pv[i].y * scp;
    o.z = v[i].z * sc + gate * pv[i].z * scp;
    o.w = v[i].w * sc + gate * pv[i].w * scp;
    *reinterpret_cast<float4*>(x0 + (size_t)tok * 1024 + c) = o;
    float4 yy;
    yy.x = a0 * o.x + b0 * o.x; yy.y = a0 * o.y + b0 * o.y;
    yy.z = a0 * o.z + b0 * o.z; yy.w = a0 * o.w + b0 * o.w;
    *reinterpret_cast<float4*>(x + (size_t)tok * 1024 + c) = yy;
    y[i] = yy;
    ssy += yy.x * yy.x + yy.y * yy.y + yy.z * yy.z + yy.w * yy.w;
  }
#pragma unroll
  for (int m = 1; m < 64; m <<= 1) ssy += __shfl_xor(ssy, m);
  const float scy = 1.f / sqrtf(ssy * (1.f / 1024.f) + eps);
#pragma unroll
  for (int i = 0; i < 4; ++i) {
    const int c = i * 256 + lane * 4;
    ushort4 u;
    u.x = f2bf(y[i].x * scy); u.y = f2bf(y[i].y * scy);
    u.z = f2bf(y[i].z * scy); u.w = f2bf(y[i].w * scy);
    *reinterpret_cast<ushort4*>(xn + (size_t)tok * 1024 + c) = u;
  }
}

// ------------- residual mix + split-K partial reduce + rmsnorm -------------
// x <- a*(x + sum_{p<np} parts[p]) + b*x0   (a=1,b=0 when combine==0)
// writes x back when it changed; xn <- rms(x) in bf16.
// parts: np contiguous [2048][1024] f32 planes (plane stride 2048*1024).

extern "C" __global__ __launch_bounds__(256)
void rmsnorm_kernel(float* __restrict__ x, const float* __restrict__ x0,
                    const float* __restrict__ parts, int np,
                    const float* __restrict__ residc, const float* __restrict__ x0c,
                    int layer, int combine, unsigned short* __restrict__ xn) {
  const int wid = threadIdx.x >> 6, lane = threadIdx.x & 63;
  const int tok = blockIdx.x * 4 + wid;
  float* xr = x + (size_t)tok * 1024;
  const float* x0r = x0 + (size_t)tok * 1024;
  float a = 1.f, bb = 0.f;
  if (combine) { a = residc[layer]; bb = x0c[layer]; }
  float4 v[4];
  float ss = 0.f;
#pragma unroll
  for (int i = 0; i < 4; ++i) {
    const int c = i * 256 + lane * 4;
    float4 xv = *reinterpret_cast<const float4*>(xr + c);
    for (int pi = 0; pi < np; ++pi) {
      const float4 pv = *reinterpret_cast<const float4*>(
          parts + (size_t)pi * 2048 * 1024 + (size_t)tok * 1024 + c);
      xv.x += pv.x; xv.y += pv.y; xv.z += pv.z; xv.w += pv.w;
    }
    if (combine) {
      const float4 ov = *reinterpret_cast<const float4*>(x0r + c);
      xv.x = a * xv.x + bb * ov.x; xv.y = a * xv.y + bb * ov.y;
      xv.z = a * xv.z + bb * ov.z; xv.w = a * xv.w + bb * ov.w;
    }
    if (combine || np > 0) *reinterpret_cast<float4*>(xr + c) = xv;
    v[i] = xv;
    ss += xv.x * xv.x + xv.y * xv.y + xv.z * xv.z + xv.w * xv.w;
  }
#pragma unroll
  for (int m = 1; m < 64; m <<= 1) ss += __shfl_xor(ss, m);
  const float sc = 1.f / sqrtf(ss * (1.f / 1024.f) + 1.1920929e-7f);
#pragma unroll
  for (int i = 0; i < 4; ++i) {
    const int c = i * 256 + lane * 4;
    ushort4 u;
    u.x = f2bf(v[i].x * sc); u.y = f2bf(v[i].y * sc);
    u.z = f2bf(v[i].z * sc); u.w = f2bf(v[i].w * sc);
    *reinterpret_cast<ushort4*>(xn + (size_t)tok * 1024 + c) = u;
  }
}

// ------------------- qkv post: rope + rms + ve-gate -> bf16 ----------------
// one wave per token; lane owns 16 contiguous channels (head = lane/4).
// qkv arrives as TWO split-K partial planes (qkv0 + qkv1), summed here.

extern "C" __global__ __launch_bounds__(256)
void qkv_post_kernel(const float* __restrict__ qkv0, const float* __restrict__ qkv1,
                     const unsigned short* __restrict__ xn,
                     const int* __restrict__ ids,
                     const float* __restrict__ ve_tab, const float* __restrict__ ve_gate_w,
                     const float* __restrict__ cost, const float* __restrict__ sint,
                     unsigned short* __restrict__ qb, unsigned short* __restrict__ kbuf,
                     unsigned short* __restrict__ vb) {
  const int wid = threadIdx.x >> 6, lane = threadIdx.x & 63;
  const int tok = blockIdx.x * 4 + wid;
  const int t = tok & 1023;
  const float eps = 1.1920929e-7f;
  const float* rowA = qkv0 + (size_t)tok * 1536;
  const float* rowB = qkv1 + (size_t)tok * 1536;
  const bool x1half = (lane & 2) == 0;   // lane%4 in {0,1}: x1; {2,3}: x2
  const int i0 = (lane & 1) << 4;        // rotary index base within half

  // ---- Q: 16 heads * 64, scale = 1.2/8 folded in ----
  {
    float v[16], p[16];
    {
      const float4* ra = reinterpret_cast<const float4*>(rowA + lane * 16);
      const float4* rb = reinterpret_cast<const float4*>(rowB + lane * 16);
#pragma unroll
      for (int i = 0; i < 4; ++i) {
        const float4 qa = ra[i], qb4 = rb[i];
        v[i * 4] = qa.x + qb4.x; v[i * 4 + 1] = qa.y + qb4.y;
        v[i * 4 + 2] = qa.z + qb4.z; v[i * 4 + 3] = qa.w + qb4.w;
      }
    }
#pragma unroll
    for (int i = 0; i < 16; ++i) p[i] = __shfl_xor(v[i], 2);
    float out[16]; float ssq = 0.f;
#pragma unroll
    for (int i = 0; i < 16; ++i) {
      const float c = cost[t * 32 + i0 + i];
      const float s = sint[t * 32 + i0 + i];
      out[i] = x1half ? (v[i] * c + p[i] * s) : (v[i] * c - p[i] * s);
      ssq += out[i] * out[i];
    }
    ssq += __shfl_xor(ssq, 1);
    ssq += __shfl_xor(ssq, 2);
    const float sc = 0.15f / sqrtf(ssq * (1.f / 64.f) + eps);
#pragma unroll
    for (int i = 0; i < 16; i += 4) {
      ushort4 u;
      u.x = f2bf(out[i] * sc); u.y = f2bf(out[i + 1] * sc);
      u.z = f2bf(out[i + 2] * sc); u.w = f2bf(out[i + 3] * sc);
      *reinterpret_cast<ushort4*>(qb + (size_t)tok * 1024 + lane * 16 + i) = u;
    }
  }
  const int kl = lane & 15;  // lanes 16-63 mirror 0-15 (keeps shfl uniform)
  // ---- K: 4 kv heads * 64, scale 1.2 ----
  {
    float v[16], p[16];
    {
      const float4* ra = reinterpret_cast<const float4*>(rowA + 1024 + kl * 16);
      const float4* rb = reinterpret_cast<const float4*>(rowB + 1024 + kl * 16);
#pragma unroll
      for (int i = 0; i < 4; ++i) {
        const float4 qa = ra[i], qb4 = rb[i];
        v[i * 4] = qa.x + qb4.x; v[i * 4 + 1] = qa.y + qb4.y;
        v[i * 4 + 2] = qa.z + qb4.z; v[i * 4 + 3] = qa.w + qb4.w;
      }
    }
#pragma unroll
    for (int i = 0; i < 16; ++i) p[i] = __shfl_xor(v[i], 2);
    float out[16]; float ssq = 0.f;
#pragma unroll
    for (int i = 0; i < 16; ++i) {
      const float c = cost[t * 32 + i0 + i];
      const float s = sint[t * 32 + i0 + i];
      out[i] = x1half ? (v[i] * c + p[i] * s) : (v[i] * c - p[i] * s);
      ssq += out[i] * out[i];
    }
    ssq += __shfl_xor(ssq, 1);
    ssq += __shfl_xor(ssq, 2);
    const float sc = 1.2f / sqrtf(ssq * (1.f / 64.f) + eps);
    if (lane < 16) {
#pragma unroll
      for (int i = 0; i < 16; i += 4) {
        ushort4 u;
        u.x = f2bf(out[i] * sc); u.y = f2bf(out[i + 1] * sc);
        u.z = f2bf(out[i + 2] * sc); u.w = f2bf(out[i + 3] * sc);
        *reinterpret_cast<ushort4*>(kbuf + (size_t)tok * 256 + kl * 16 + i) = u;
      }
    }
  }
  // ---- V: optional value-embedding gate ----
  {
    float v[16];
    {
      const float4* ra = reinterpret_cast<const float4*>(rowA + 1280 + kl * 16);
      const float4* rb = reinterpret_cast<const float4*>(rowB + 1280 + kl * 16);
#pragma unroll
      for (int i = 0; i < 4; ++i) {
        const float4 qa = ra[i], qb4 = rb[i];
        v[i * 4] = qa.x + qb4.x; v[i * 4 + 1] = qa.y + qb4.y;
        v[i * 4 + 2] = qa.z + qb4.z; v[i * 4 + 3] = qa.w + qb4.w;
      }
    }
    if (ve_tab != nullptr) {
      const int kvh = kl >> 2;
      float g = 0.f;
#pragma unroll
      for (int c = 0; c < 12; ++c)
        g += bf2f(xn[(size_t)tok * 1024 + c]) * ve_gate_w[kvh * 12 + c];
      g = 3.f / (1.f + __expf(-g));
      const float* ver = ve_tab + (size_t)ids[tok] * 256 + kl * 16;
#pragma unroll
      for (int i = 0; i < 16; ++i) v[i] += g * ver[i];
    }
    if (lane < 16) {
#pragma unroll
      for (int i = 0; i < 16; i += 4) {
        ushort4 u;
        u.x = f2bf(v[i]); u.y = f2bf(v[i + 1]); u.z = f2bf(v[i + 2]); u.w = f2bf(v[i + 3]);
        *reinterpret_cast<ushort4*>(vb + (size_t)tok * 256 + kl * 16 + i) = u;
      }
    }
  }
}

// ---------------- V transpose: vb[b][t][kv*64+d] -> vt[b*4+kv][d][t] -------

extern "C" __global__ __launch_bounds__(256)
void vtrans_kernel(const unsigned short* __restrict__ vb, unsigned short* __restrict__ vt) {
  __shared__ unsigned short tile[64][72];
  const int t0 = blockIdx.x << 6;
  const int bk = blockIdx.y;               // b*4 + kv
  const int tid = threadIdx.x;
  {
    const int r = tid >> 2, cs = (tid & 3) << 4;
    const unsigned short* src = vb + ((size_t)((bk >> 2) * 1024 + t0 + r)) * 256 + (bk & 3) * 64 + cs;
    *reinterpret_cast<uint4*>(&tile[r][cs]) = *reinterpret_cast<const uint4*>(src);
    *reinterpret_cast<uint4*>(&tile[r][cs + 8]) = *reinterpret_cast<const uint4*>(src + 8);
  }
  __syncthreads();
  {
    const int d = tid >> 2, ts = (tid & 3) << 4;
    unsigned int w[8];
#pragma unroll
    for (int i = 0; i < 8; ++i)
      w[i] = (unsigned int)tile[ts + 2 * i][d] | ((unsigned int)tile[ts + 2 * i + 1][d] << 16);
    unsigned short* dst = vt + ((size_t)bk * 64 + d) * 1024 + t0 + ts;
    uint4 u0; u0.x = w[0]; u0.y = w[1]; u0.z = w[2]; u0.w = w[3];
    uint4 u1; u1.x = w[4]; u1.y = w[5]; u1.z = w[6]; u1.w = w[7];
    *reinterpret_cast<uint4*>(dst) = u0;
    *reinterpret_cast<uint4*>(dst + 8) = u1;
  }
}

// --------------------------- flash attention -------------------------------
// 1 wave per (b, h, 16-query block). Swapped QK^T: St[key][query] via
// mfma(K, Q); softmax reduce over lane groups; P -> LDS -> PV A-operand;
// V^T rows give contiguous PV B-operand.

extern "C" __global__ __launch_bounds__(64)
void attn_kernel(const unsigned short* __restrict__ qb,
                 const unsigned short* __restrict__ kb,
                 const unsigned short* __restrict__ vt,
                 unsigned short* __restrict__ y, int W) {
  __shared__ unsigned short p_lds[16 * 32];
  const int lane = threadIdx.x;
  const int q0 = blockIdx.x << 4;
  const int h = blockIdx.y;
  const int b = blockIdx.z;
  const int kv = h >> 2;
  const int lr = lane & 15, lk = lane >> 4;

  bf16x8 qf0, qf1;
  {
    const unsigned short* qrow = qb + ((size_t)(b * 1024 + q0 + lr)) * 1024 + h * 64 + (lk << 3);
    qf0 = *reinterpret_cast<const bf16x8*>(qrow);
    qf1 = *reinterpret_cast<const bf16x8*>(qrow + 32);
  }
  f32x4 acc[4] = {};
  float m_run = -3e38f, l_run = 0.f;
  int kstart = q0 - W + 1; if (kstart < 0) kstart = 0;
  kstart &= ~31;
  const int qq = q0 + lr;

  for (int kb0 = kstart; kb0 < q0 + 16; kb0 += 32) {
    f32x4 st[2];
#pragma unroll
    for (int s = 0; s < 2; ++s) {
      const unsigned short* krow = kb + ((size_t)(b * 1024 + kb0 + (s << 4) + lr)) * 256 + kv * 64 + (lk << 3);
      bf16x8 kf0 = *reinterpret_cast<const bf16x8*>(krow);
      bf16x8 kf1 = *reinterpret_cast<const bf16x8*>(krow + 32);
      f32x4 z = {0.f, 0.f, 0.f, 0.f};
      z = __builtin_amdgcn_mfma_f32_16x16x32_bf16(kf0, qf0, z, 0, 0, 0);
      st[s] = __builtin_amdgcn_mfma_f32_16x16x32_bf16(kf1, qf1, z, 0, 0, 0);
    }
    float sv[8];
    float bm = -3e38f;
#pragma unroll
    for (int s = 0; s < 2; ++s)
#pragma unroll
      for (int j = 0; j < 4; ++j) {
        const int key = kb0 + (s << 4) + (lk << 2) + j;
        const bool valid = (key <= qq) && (qq - key < W);
        const float xx = valid ? st[s][j] : -3e38f;
        sv[s * 4 + j] = xx;
        bm = fmaxf(bm, xx);
      }
    bm = fmaxf(bm, __shfl_xor(bm, 16));
    bm = fmaxf(bm, __shfl_xor(bm, 32));
    const float m_new = fmaxf(m_run, bm);
    const float alpha = __expf(m_run - m_new);
    float psum = 0.f;
    unsigned short pbv[8];
#pragma unroll
    for (int s = 0; s < 2; ++s)
#pragma unroll
      for (int j = 0; j < 4; ++j) {
        const int key = kb0 + (s << 4) + (lk << 2) + j;
        const bool valid = (key <= qq) && (qq - key < W);
        const float pv = valid ? __expf(sv[s * 4 + j] - m_new) : 0.f;
        psum += pv;
        pbv[s * 4 + j] = f2bf(pv);
      }
    psum += __shfl_xor(psum, 16);
    psum += __shfl_xor(psum, 32);
    l_run = l_run * alpha + psum;
    m_run = m_new;

    __syncthreads();  // WAR vs previous iteration's reads
    {
      ushort4 u0, u1;
      u0.x = pbv[0]; u0.y = pbv[1]; u0.z = pbv[2]; u0.w = pbv[3];
      u1.x = pbv[4]; u1.y = pbv[5]; u1.z = pbv[6]; u1.w = pbv[7];
      *reinterpret_cast<ushort4*>(p_lds + lr * 32 + (lk << 2)) = u0;
      *reinterpret_cast<ushort4*>(p_lds + lr * 32 + 16 + (lk << 2)) = u1;
    }
    __syncthreads();
    const bf16x8 pf = *reinterpret_cast<const bf16x8*>(p_lds + lr * 32 + (lk << 3));
    float al[4];
#pragma unroll
    for (int j = 0; j < 4; ++j) al[j] = __shfl(alpha, (lk << 2) + j);
#pragma unroll
    for (int d = 0; d < 4; ++d) {
      const unsigned short* vrow = vt + ((size_t)((b * 4 + kv) * 64 + (d << 4) + lr)) * 1024 + kb0 + (lk << 3);
      const bf16x8 vf = *reinterpret_cast<const bf16x8*>(vrow);
#pragma unroll
      for (int j = 0; j < 4; ++j) acc[d][j] *= al[j];
      acc[d] = __builtin_amdgcn_mfma_f32_16x16x32_bf16(pf, vf, acc[d], 0, 0, 0);
    }
  }
  float linv[4];
#pragma unroll
  for (int j = 0; j < 4; ++j) linv[j] = 1.f / __shfl(l_run, (lk << 2) + j);
#pragma unroll
  for (int d = 0; d < 4; ++d)
#pragma unroll
    for (int j = 0; j < 4; ++j) {
      const int qrow = q0 + (lk << 2) + j;
      y[((size_t)(b * 1024 + qrow)) * 1024 + h * 64 + (d << 4) + lr] = f2bf(acc[d][j] * linv[j]);
    }
}

// ------------------------------ generic GEMM -------------------------------
// C[M,N] = A[M,K] (bf16, row-major) @ Bw[N,K]^T (bf16, row-major = weights)
// EPI: 0 store f32 (split-K partial plane z), 2 relu^2 -> bf16, 3 softcap f32
// NJ: fragments per wave along N; tile is 128 x (NJ*32). BK=32.
// Double-buffered LDS (R5 structure, measured best): stage(t+1) is issued
// BEFORE the MFMA cluster of t; ONE __syncthreads per K-step.
// Operand-swapped MFMA: D = mfma(B_frag, A_frag) computes the C^T tile ->
// each thread's 4-reg quad spans 4 CONSECUTIVE N columns -> float4 stores.
// XCD swizzle (T1): bijective chunked remap when nwg%8==0.

template <int EPI, int NJ>
__global__ __launch_bounds__(256)
void gemm_bf16(const unsigned short* __restrict__ A,
               const unsigned short* __restrict__ Bw,
               const float* __restrict__ Cin, void* __restrict__ Cout,
               int M, int N, int K, int kchunk) {
  constexpr int BN = NJ * 32;
  __shared__ unsigned short sA[2][128 * 32];
  __shared__ unsigned short sB[2][BN * 32];
  const int tid = threadIdx.x;

  int flat = blockIdx.x + gridDim.x * blockIdx.y;
  const int nwg = gridDim.x * gridDim.y;
  if ((nwg & 7) == 0) flat = (flat & 7) * (nwg >> 3) + (flat >> 3);
  const int m0 = (flat % gridDim.x) << 7;
  const int n0 = (flat / gridDim.x) * BN;
  const int k_begin = blockIdx.z * kchunk;
  int k_end = k_begin + kchunk; if (k_end > K) k_end = K;

  const int wid = tid >> 6, lane = tid & 63;
  const int wr = wid >> 1, wc = wid & 1;
  const int lr = lane & 15, lk = lane >> 4;

  // staging geometry: thread tid covers row=tid>>2 (0..63), ch=(tid&3)*8
  const int row0 = tid >> 2, ch0 = (tid & 3) << 3;
  const unsigned short* gA0 = A + (size_t)(m0 + row0) * K + ch0;
  const unsigned short* gA1 = gA0 + (size_t)64 * K;
  const unsigned short* gB0 = Bw + (size_t)(n0 + row0) * K + ch0;
  const unsigned short* gB1 = gB0 + (size_t)64 * K;
  const int lofs = wid << 9;              // wave-uniform LDS base (shorts)

  auto stage = [&](int buf, int k0) {
    gload16(gA0 + k0, sA[buf] + lofs);
    gload16(gA1 + k0, sA[buf] + lofs + 2048);
    gload16(gB0 + k0, sB[buf] + lofs);
    if constexpr (NJ == 4) gload16(gB1 + k0, sB[buf] + lofs + 2048);
  };

  f32x4 acc[4][NJ] = {};
  int cur = 0;
  stage(0, k_begin);
  __syncthreads();                        // drain prologue stage
  for (int k0 = k_begin; k0 < k_end; k0 += 32) {
    // issue ds_reads of current tile
    bf16x8 af[4], bfr[NJ];
#pragma unroll
    for (int i = 0; i < 4; ++i)
      af[i] = *reinterpret_cast<const bf16x8*>(sA[cur] + ((wr << 6) + (i << 4) + lr) * 32 + (lk << 3));
#pragma unroll
    for (int j = 0; j < NJ; ++j)
      bfr[j] = *reinterpret_cast<const bf16x8*>(sB[cur] + (wc * (BN / 2) + (j << 4) + lr) * 32 + (lk << 3));
    // issue next tile's staging loads (in flight during MFMA below)
    const int nxt = k0 + 32;
    if (nxt < k_end) stage(cur ^ 1, nxt);
#pragma unroll
    for (int i = 0; i < 4; ++i)
#pragma unroll
      for (int j = 0; j < NJ; ++j)
        acc[i][j] = __builtin_amdgcn_mfma_f32_16x16x32_bf16(bfr[j], af[i], acc[i][j], 0, 0, 0);
    __syncthreads();                      // drains next-stage vmcnt + WAR
    cur ^= 1;
  }
  // C^T fragment layout: acc[i][j] reg e -> C[m][n], m = mbase + i*16,
  // n = nbase + j*16 + e (4 consecutive N cols per reg quad).
  const int mbase = m0 + (wr << 6) + lr;
  const int nbase = n0 + wc * (BN / 2) + (lk << 2);
  float* outF = (float*)Cout + (size_t)blockIdx.z * M * N;   // partial plane
#pragma unroll
  for (int i = 0; i < 4; ++i)
#pragma unroll
    for (int j = 0; j < NJ; ++j) {
      const int m = mbase + (i << 4);
      const int n = nbase + (j << 4);
      const size_t off = (size_t)m * N + n;
      f32x4 v = acc[i][j];
      if (EPI == 0) {
        *reinterpret_cast<f32x4*>(outF + off) = v;
      } else if (EPI == 1) {
        const f32x4 c = *reinterpret_cast<const f32x4*>(Cin + off);
        *reinterpret_cast<f32x4*>((float*)Cout + off) = c + v;
      } else if (EPI == 2) {
        ushort4 u;
        float r0 = v[0] > 0.f ? v[0] : 0.f;
        float r1 = v[1] > 0.f ? v[1] : 0.f;
        float r2 = v[2] > 0.f ? v[2] : 0.f;
        float r3 = v[3] > 0.f ? v[3] : 0.f;
        u.x = f2bf(r0 * r0); u.y = f2bf(r1 * r1);
        u.z = f2bf(r2 * r2); u.w = f2bf(r3 * r3);
        *reinterpret_cast<ushort4*>((unsigned short*)Cout + off) = u;
      } else {
        // 15*tanh(v/15) = 15 - 30/(exp(2v/15)+1); saturates correctly
        f32x4 o;
#pragma unroll
        for (int e = 0; e < 4; ++e) {
          const float ex = __expf(v[e] * (2.f / 15.f));
          o[e] = 15.f - 30.f / (ex + 1.f);
        }
        *reinterpret_cast<f32x4*>((float*)Cout + off) = o;
      }
    }
}

// ------------------------------- launcher ----------------------------------

extern "C" void kernel_launch(void* const* d_in, const int* in_sizes, int n_in,
                              void* d_out, int out_size, void* d_ws, size_t ws_size,
                              hipStream_t stream) {
  (void)in_sizes; (void)n_in; (void)out_size; (void)ws_size;
  const int*   ids  = (const int*)  d_in[0];
  const float* wte  = (const float*)d_in[1];
  const float* Wq   = (const float*)d_in[2];
  const float* Wk   = (const float*)d_in[3];
  const float* Wv   = (const float*)d_in[4];
  const float* Wo   = (const float*)d_in[5];
  const float* Wfc  = (const float*)d_in[6];
  const float* Wmp  = (const float*)d_in[7];
  const float* VeT  = (const float*)d_in[8];
  const float* VeG  = (const float*)d_in[9];
  const float* LmW  = (const float*)d_in[10];
  const float* ResC = (const float*)d_in[11];
  const float* X0C  = (const float*)d_in[12];
  const float* SmW  = (const float*)d_in[13];
  const float* SmL  = (const float*)d_in[14];

  char* p = (char*)d_ws;
  auto alloc = [&](size_t bytes) -> char* {
    char* r = p; p += (bytes + 255) & ~(size_t)255; return r;
  };
  float* x  = (float*)alloc((size_t)2048 * 1024 * 4);
  float* x0 = (float*)alloc((size_t)2048 * 1024 * 4);
  unsigned short* xn = (unsigned short*)alloc((size_t)2048 * 1024 * 2);
  unsigned short* hidden = (unsigned short*)alloc((size_t)2048 * 4096 * 2);
  float* qkvp = (float*)alloc((size_t)2 * 2048 * 1536 * 4);   // qkv split-K partials
  float* wop  = (float*)alloc((size_t)2 * 2048 * 1024 * 4);   // Wo split-K partials
  float* mpp  = (float*)alloc((size_t)4 * 2048 * 1024 * 4);   // MP split-K partials
  unsigned short* qbuf = (unsigned short*)alloc((size_t)2048 * 1024 * 2);
  unsigned short* kbuf = (unsigned short*)alloc((size_t)2048 * 256 * 2);
  unsigned short* vbuf = (unsigned short*)alloc((size_t)2048 * 256 * 2);
  unsigned short* vtb  = (unsigned short*)alloc((size_t)2048 * 256 * 2);
  unsigned short* ybuf = (unsigned short*)alloc((size_t)2048 * 1024 * 2);
  float* cost = (float*)alloc((size_t)1024 * 32 * 4);
  float* sint = (float*)alloc((size_t)1024 * 32 * 4);
  unsigned short* wqkv = (unsigned short*)alloc((size_t)6 * 1536 * 1024 * 2);
  unsigned short* wo   = (unsigned short*)alloc((size_t)6 * 1024 * 1024 * 2);
  unsigned short* wfc  = (unsigned short*)alloc((size_t)6 * 4096 * 1024 * 2);
  unsigned short* wmp  = (unsigned short*)alloc((size_t)6 * 1024 * 4096 * 2);
  unsigned short* wlm  = (unsigned short*)alloc((size_t)32000 * 1024 * 2);

  // merged weight conversion: 12,353,536 vectors / 256 = 48,256 blocks
  prep_weights_kernel<<<48256, 256, 0, stream>>>(Wq, Wk, Wv, Wo, Wfc, Wmp, LmW,
                                                 wqkv, wo, wfc, wmp, wlm);
  rope_tab_kernel<<<128, 256, 0, stream>>>(cost, sint);
  embed_kernel<<<512, 256, 0, stream>>>(ids, wte, SmW, SmL, ResC, X0C, x, x0, xn);

  static const int WIN[6] = {256, 1024, 256, 1024, 256, 1024};
  for (int l = 0; l < 6; ++l) {
    // layer-start combine (l=0 fused into embed); l>0 folds in prev MP partials
    if (l > 0)
      rmsnorm_kernel<<<512, 256, 0, stream>>>(x, x0, mpp, 4, ResC, X0C, l, 1, xn);
    // QKV: split-K x2 -> two partial planes (summed inside qkv_post)
    gemm_bf16<0, 2><<<dim3(16, 24, 2), 256, 0, stream>>>(xn, wqkv + (size_t)l * 1536 * 1024,
                                                         nullptr, qkvp, 2048, 1536, 1024, 512);
    const float* vtab = nullptr; const float* vgw = nullptr;
    if (l == 1 || l == 3 || l == 5) {
      const int vi = (l - 1) / 2;
      vtab = VeT + (size_t)vi * 32000 * 256;
      vgw  = VeG + vi * 48;
    }
    qkv_post_kernel<<<512, 256, 0, stream>>>(qkvp, qkvp + (size_t)2048 * 1536, xn, ids,
                                             vtab, vgw, cost, sint, qbuf, kbuf, vbuf);
    vtrans_kernel<<<dim3(16, 8), 256, 0, stream>>>(vbuf, vtb);
    attn_kernel<<<dim3(64, 16, 2), 64, 0, stream>>>(qbuf, kbuf, vtb, ybuf, WIN[l]);
    // Wo: split-K x2 -> partials (reduced + added to x by next rmsnorm)
    gemm_bf16<0, 2><<<dim3(16, 16, 2), 256, 0, stream>>>(ybuf, wo + (size_t)l * 1024 * 1024,
                                                         nullptr, wop, 2048, 1024, 1024, 512);
    rmsnorm_kernel<<<512, 256, 0, stream>>>(x, x0, wop, 2, ResC, X0C, l, 0, xn);
    gemm_bf16<2, 4><<<dim3(16, 32), 256, 0, stream>>>(xn, wfc + (size_t)l * 4096 * 1024,
                                                      nullptr, hidden, 2048, 4096, 1024, 1024);
    // MP: split-K x4 (K=4096) -> partials (reduced by next layer's rmsnorm)
    gemm_bf16<0, 2><<<dim3(16, 16, 4), 256, 0, stream>>>(hidden, wmp + (size_t)l * 1024 * 4096,
                                                         nullptr, mpp, 2048, 1024, 4096, 1024);
  }
  rmsnorm_kernel<<<512, 256, 0, stream>>>(x, x0, mpp, 4, ResC, X0C, 0, 0, xn);
  gemm_bf16<3, 4><<<dim3(16, 250), 256, 0, stream>>>(xn, wlm, nullptr, (float*)d_out,
                                                     2048, 32000, 1024, 1024);
}

// Round 9
// 1371.808 us; speedup vs baseline: 1.1784x; 1.0142x over previous
//
#include <hip/hip_runtime.h>
#include <stdint.h>
#include <math.h>

// ---------------------------------------------------------------------------
// NanochatMiniLM forward on MI355X. Round 9: gemm512 — same 128x128 tile and
// R5 single-barrier dbuf schedule, but 8 waves/block (512 thr). Per-wave
// acc drops 64->32 AGPRs (gfx950 unified VGPR/AGPR file was the hidden
// occupancy cap: 72 arch + 64 acc ~= 136 -> 3 waves/SIMD = the measured 30%).
// Staging becomes 2 gload_lds per thread (512x16B = one 128x32 half-tile).
// Applied to LM/FC/MP/QKV; Wo keeps the 256-thread kernel (grid too small).
// Split-K partial planes + fused reduction, C^T epilogue, fast softcap,
// XCD swizzle, merged prologue, embed-fused l=0 rmsnorm retained.
// B=2 T=1024 D=1024 H=16 KV=4 HD=64 L=6 VP=32000, windows {256,1024,...}
// ---------------------------------------------------------------------------

using bf16x8 = __attribute__((ext_vector_type(8))) short;   // 8 bf16 (4 VGPRs)
using f32x4  = __attribute__((ext_vector_type(4))) float;   // 4 f32 acc

#define DEV static __device__ __forceinline__

DEV unsigned short f2bf(float f) {            // RNE f32 -> bf16 bits
  unsigned int x = __builtin_bit_cast(unsigned int, f);
  x += 0x7fffu + ((x >> 16) & 1u);
  return (unsigned short)(x >> 16);
}
DEV float bf2f(unsigned short u) {
  return __builtin_bit_cast(float, (unsigned int)u << 16);
}
DEV unsigned int packbf2(float a, float b) {
  return (unsigned int)f2bf(a) | ((unsigned int)f2bf(b) << 16);
}

// async global->LDS, 16B per lane; LDS dest is wave-uniform base + lane*16
DEV void gload16(const unsigned short* g, unsigned short* l) {
  __builtin_amdgcn_global_load_lds(
      (__attribute__((address_space(1))) void*)const_cast<unsigned short*>(g),
      (__attribute__((address_space(3))) void*)l, 16, 0, 0);
}

// ------------------- merged weight conversion (one launch) -----------------

extern "C" __global__ __launch_bounds__(256)
void prep_weights_kernel(const float* __restrict__ Wq, const float* __restrict__ Wk,
                         const float* __restrict__ Wv, const float* __restrict__ Wo,
                         const float* __restrict__ Wfc, const float* __restrict__ Wmp,
                         const float* __restrict__ LmW,
                         unsigned short* __restrict__ wqkv, unsigned short* __restrict__ wo,
                         unsigned short* __restrict__ wfc, unsigned short* __restrict__ wmp,
                         unsigned short* __restrict__ wlm) {
  const long v = (long)blockIdx.x * 256 + threadIdx.x;   // vector index
  const long S0 = 1179648, S1 = S0 + 786432, S2 = S1 + 3145728,
             S3 = S2 + 3145728, S4 = S3 + 4096000;
  const float* src; unsigned short* dst;
  if (v < S0) {
    const long i = v * 8;
    const int c = (int)(i & 1023);
    const int row = (int)(i >> 10);
    const int l = row / 1536, r = row - l * 1536;
    if (r < 1024)      src = Wq + ((size_t)l * 1024 + r) * 1024 + c;
    else if (r < 1280) src = Wk + ((size_t)l * 256 + (r - 1024)) * 1024 + c;
    else               src = Wv + ((size_t)l * 256 + (r - 1280)) * 1024 + c;
    dst = wqkv + i;
  } else if (v < S1) {
    const long i = (v - S0) * 8; src = Wo + i;  dst = wo + i;
  } else if (v < S2) {
    const long i = (v - S1) * 8; src = Wfc + i; dst = wfc + i;
  } else if (v < S3) {
    const long i = (v - S2) * 8; src = Wmp + i; dst = wmp + i;
  } else if (v < S4) {
    const long i = (v - S3) * 8; src = LmW + i; dst = wlm + i;
  } else {
    return;
  }
  const float4 a = *reinterpret_cast<const float4*>(src);
  const float4 b = *reinterpret_cast<const float4*>(src + 4);
  uint4 u;
  u.x = packbf2(a.x, a.y); u.y = packbf2(a.z, a.w);
  u.z = packbf2(b.x, b.y); u.w = packbf2(b.z, b.w);
  *reinterpret_cast<uint4*>(dst) = u;
}

// ------------------------------- rope tables -------------------------------

extern "C" __global__ __launch_bounds__(256)
void rope_tab_kernel(float* __restrict__ cost, float* __restrict__ sint) {
  const int idx = blockIdx.x * 256 + threadIdx.x;   // t*32 + i, 32768 total
  const int t = idx >> 5, i = idx & 31;
  const double inv = exp(((double)i * (-1.0 / 32.0)) * log(100000.0));
  const double f = (double)t * inv;
  cost[idx] = (float)cos(f);
  sint[idx] = (float)sin(f);
}

// ------------- embedding + rms + smear + fused l=0 combine+rms -------------

extern "C" __global__ __launch_bounds__(256)
void embed_kernel(const int* __restrict__ ids, const float* __restrict__ wte,
                  const float* __restrict__ smear_w, const float* __restrict__ smear_l,
                  const float* __restrict__ residc, const float* __restrict__ x0c,
                  float* __restrict__ x, float* __restrict__ x0,
                  unsigned short* __restrict__ xn) {
  const int wid = threadIdx.x >> 6, lane = threadIdx.x & 63;
  const int tok = blockIdx.x * 4 + wid;
  const int t = tok & 1023;
  const float eps = 1.1920929e-7f;

  const float* wrow = wte + (size_t)ids[tok] * 1024;
  float4 v[4];
  float ss = 0.f;
#pragma unroll
  for (int i = 0; i < 4; ++i) {
    v[i] = *reinterpret_cast<const float4*>(wrow + i * 256 + lane * 4);
    ss += v[i].x * v[i].x + v[i].y * v[i].y + v[i].z * v[i].z + v[i].w * v[i].w;
  }
#pragma unroll
  for (int m = 1; m < 64; m <<= 1) ss += __shfl_xor(ss, m);
  const float sc = 1.f / sqrtf(ss * (1.f / 1024.f) + eps);

  float4 pv[4];
#pragma unroll
  for (int i = 0; i < 4; ++i) { pv[i].x = 0.f; pv[i].y = 0.f; pv[i].z = 0.f; pv[i].w = 0.f; }
  float scp = 0.f, gate = 0.f;
  if (t > 0) {
    const float* prow = wte + (size_t)ids[tok - 1] * 1024;
    float ssp = 0.f;
#pragma unroll
    for (int i = 0; i < 4; ++i) {
      pv[i] = *reinterpret_cast<const float4*>(prow + i * 256 + lane * 4);
      ssp += pv[i].x * pv[i].x + pv[i].y * pv[i].y + pv[i].z * pv[i].z + pv[i].w * pv[i].w;
    }
#pragma unroll
    for (int m = 1; m < 64; m <<= 1) ssp += __shfl_xor(ssp, m);
    scp = 1.f / sqrtf(ssp * (1.f / 1024.f) + eps);
    float gp = 0.f;
    if (lane < 6) {
      gp = v[0].x * smear_w[lane * 4] + v[0].y * smear_w[lane * 4 + 1] +
           v[0].z * smear_w[lane * 4 + 2] + v[0].w * smear_w[lane * 4 + 3];
      gp *= sc;
    }
#pragma unroll
    for (int m = 1; m < 64; m <<= 1) gp += __shfl_xor(gp, m);
    gate = smear_l[0] / (1.f + __expf(-gp));
  }
  const float a0 = residc[0], b0 = x0c[0];
  float4 y[4];
  float ssy = 0.f;
#pragma unroll
  for (int i = 0; i < 4; ++i) {
    const int c = i * 256 + lane * 4;
    float4 o;
    o.x = v[i].x * sc + gate * pv[i].x * scp;
    o.y = v[i].y * sc + gate * pv[i].y * scp;
    o.z = v[i].z * sc + gate * pv[i].z * scp;
    o.w = v[i].w * sc + gate * pv[i].w * scp;
    *reinterpret_cast<float4*>(x0 + (size_t)tok * 1024 + c) = o;
    float4 yy;
    yy.x = a0 * o.x + b0 * o.x; yy.y = a0 * o.y + b0 * o.y;
    yy.z = a0 * o.z + b0 * o.z; yy.w = a0 * o.w + b0 * o.w;
    *reinterpret_cast<float4*>(x + (size_t)tok * 1024 + c) = yy;
    y[i] = yy;
    ssy += yy.x * yy.x + yy.y * yy.y + yy.z * yy.z + yy.w * yy.w;
  }
#pragma unroll
  for (int m = 1; m < 64; m <<= 1) ssy += __shfl_xor(ssy, m);
  const float scy = 1.f / sqrtf(ssy * (1.f / 1024.f) + eps);
#pragma unroll
  for (int i = 0; i < 4; ++i) {
    const int c = i * 256 + lane * 4;
    ushort4 u;
    u.x = f2bf(y[i].x * scy); u.y = f2bf(y[i].y * scy);
    u.z = f2bf(y[i].z * scy); u.w = f2bf(y[i].w * scy);
    *reinterpret_cast<ushort4*>(xn + (size_t)tok * 1024 + c) = u;
  }
}

// ------------- residual mix + split-K partial reduce + rmsnorm -------------

extern "C" __global__ __launch_bounds__(256)
void rmsnorm_kernel(float* __restrict__ x, const float* __restrict__ x0,
                    const float* __restrict__ parts, int np,
                    const float* __restrict__ residc, const float* __restrict__ x0c,
                    int layer, int combine, unsigned short* __restrict__ xn) {
  const int wid = threadIdx.x >> 6, lane = threadIdx.x & 63;
  const int tok = blockIdx.x * 4 + wid;
  float* xr = x + (size_t)tok * 1024;
  const float* x0r = x0 + (size_t)tok * 1024;
  float a = 1.f, bb = 0.f;
  if (combine) { a = residc[layer]; bb = x0c[layer]; }
  float4 v[4];
  float ss = 0.f;
#pragma unroll
  for (int i = 0; i < 4; ++i) {
    const int c = i * 256 + lane * 4;
    float4 xv = *reinterpret_cast<const float4*>(xr + c);
    for (int pi = 0; pi < np; ++pi) {
      const float4 pv = *reinterpret_cast<const float4*>(
          parts + (size_t)pi * 2048 * 1024 + (size_t)tok * 1024 + c);
      xv.x += pv.x; xv.y += pv.y; xv.z += pv.z; xv.w += pv.w;
    }
    if (combine) {
      const float4 ov = *reinterpret_cast<const float4*>(x0r + c);
      xv.x = a * xv.x + bb * ov.x; xv.y = a * xv.y + bb * ov.y;
      xv.z = a * xv.z + bb * ov.z; xv.w = a * xv.w + bb * ov.w;
    }
    if (combine || np > 0) *reinterpret_cast<float4*>(xr + c) = xv;
    v[i] = xv;
    ss += xv.x * xv.x + xv.y * xv.y + xv.z * xv.z + xv.w * xv.w;
  }
#pragma unroll
  for (int m = 1; m < 64; m <<= 1) ss += __shfl_xor(ss, m);
  const float sc = 1.f / sqrtf(ss * (1.f / 1024.f) + 1.1920929e-7f);
#pragma unroll
  for (int i = 0; i < 4; ++i) {
    const int c = i * 256 + lane * 4;
    ushort4 u;
    u.x = f2bf(v[i].x * sc); u.y = f2bf(v[i].y * sc);
    u.z = f2bf(v[i].z * sc); u.w = f2bf(v[i].w * sc);
    *reinterpret_cast<ushort4*>(xn + (size_t)tok * 1024 + c) = u;
  }
}

// ------------------- qkv post: rope + rms + ve-gate -> bf16 ----------------

extern "C" __global__ __launch_bounds__(256)
void qkv_post_kernel(const float* __restrict__ qkv0, const float* __restrict__ qkv1,
                     const unsigned short* __restrict__ xn,
                     const int* __restrict__ ids,
                     const float* __restrict__ ve_tab, const float* __restrict__ ve_gate_w,
                     const float* __restrict__ cost, const float* __restrict__ sint,
                     unsigned short* __restrict__ qb, unsigned short* __restrict__ kbuf,
                     unsigned short* __restrict__ vb) {
  const int wid = threadIdx.x >> 6, lane = threadIdx.x & 63;
  const int tok = blockIdx.x * 4 + wid;
  const int t = tok & 1023;
  const float eps = 1.1920929e-7f;
  const float* rowA = qkv0 + (size_t)tok * 1536;
  const float* rowB = qkv1 + (size_t)tok * 1536;
  const bool x1half = (lane & 2) == 0;   // lane%4 in {0,1}: x1; {2,3}: x2
  const int i0 = (lane & 1) << 4;        // rotary index base within half

  // ---- Q: 16 heads * 64, scale = 1.2/8 folded in ----
  {
    float v[16], p[16];
    {
      const float4* ra = reinterpret_cast<const float4*>(rowA + lane * 16);
      const float4* rb = reinterpret_cast<const float4*>(rowB + lane * 16);
#pragma unroll
      for (int i = 0; i < 4; ++i) {
        const float4 qa = ra[i], qb4 = rb[i];
        v[i * 4] = qa.x + qb4.x; v[i * 4 + 1] = qa.y + qb4.y;
        v[i * 4 + 2] = qa.z + qb4.z; v[i * 4 + 3] = qa.w + qb4.w;
      }
    }
#pragma unroll
    for (int i = 0; i < 16; ++i) p[i] = __shfl_xor(v[i], 2);
    float out[16]; float ssq = 0.f;
#pragma unroll
    for (int i = 0; i < 16; ++i) {
      const float c = cost[t * 32 + i0 + i];
      const float s = sint[t * 32 + i0 + i];
      out[i] = x1half ? (v[i] * c + p[i] * s) : (v[i] * c - p[i] * s);
      ssq += out[i] * out[i];
    }
    ssq += __shfl_xor(ssq, 1);
    ssq += __shfl_xor(ssq, 2);
    const float sc = 0.15f / sqrtf(ssq * (1.f / 64.f) + eps);
#pragma unroll
    for (int i = 0; i < 16; i += 4) {
      ushort4 u;
      u.x = f2bf(out[i] * sc); u.y = f2bf(out[i + 1] * sc);
      u.z = f2bf(out[i + 2] * sc); u.w = f2bf(out[i + 3] * sc);
      *reinterpret_cast<ushort4*>(qb + (size_t)tok * 1024 + lane * 16 + i) = u;
    }
  }
  const int kl = lane & 15;  // lanes 16-63 mirror 0-15 (keeps shfl uniform)
  // ---- K: 4 kv heads * 64, scale 1.2 ----
  {
    float v[16], p[16];
    {
      const float4* ra = reinterpret_cast<const float4*>(rowA + 1024 + kl * 16);
      const float4* rb = reinterpret_cast<const float4*>(rowB + 1024 + kl * 16);
#pragma unroll
      for (int i = 0; i < 4; ++i) {
        const float4 qa = ra[i], qb4 = rb[i];
        v[i * 4] = qa.x + qb4.x; v[i * 4 + 1] = qa.y + qb4.y;
        v[i * 4 + 2] = qa.z + qb4.z; v[i * 4 + 3] = qa.w + qb4.w;
      }
    }
#pragma unroll
    for (int i = 0; i < 16; ++i) p[i] = __shfl_xor(v[i], 2);
    float out[16]; float ssq = 0.f;
#pragma unroll
    for (int i = 0; i < 16; ++i) {
      const float c = cost[t * 32 + i0 + i];
      const float s = sint[t * 32 + i0 + i];
      out[i] = x1half ? (v[i] * c + p[i] * s) : (v[i] * c - p[i] * s);
      ssq += out[i] * out[i];
    }
    ssq += __shfl_xor(ssq, 1);
    ssq += __shfl_xor(ssq, 2);
    const float sc = 1.2f / sqrtf(ssq * (1.f / 64.f) + eps);
    if (lane < 16) {
#pragma unroll
      for (int i = 0; i < 16; i += 4) {
        ushort4 u;
        u.x = f2bf(out[i] * sc); u.y = f2bf(out[i + 1] * sc);
        u.z = f2bf(out[i + 2] * sc); u.w = f2bf(out[i + 3] * sc);
        *reinterpret_cast<ushort4*>(kbuf + (size_t)tok * 256 + kl * 16 + i) = u;
      }
    }
  }
  // ---- V: optional value-embedding gate ----
  {
    float v[16];
    {
      const float4* ra = reinterpret_cast<const float4*>(rowA + 1280 + kl * 16);
      const float4* rb = reinterpret_cast<const float4*>(rowB + 1280 + kl * 16);
#pragma unroll
      for (int i = 0; i < 4; ++i) {
        const float4 qa = ra[i], qb4 = rb[i];
        v[i * 4] = qa.x + qb4.x; v[i * 4 + 1] = qa.y + qb4.y;
        v[i * 4 + 2] = qa.z + qb4.z; v[i * 4 + 3] = qa.w + qb4.w;
      }
    }
    if (ve_tab != nullptr) {
      const int kvh = kl >> 2;
      float g = 0.f;
#pragma unroll
      for (int c = 0; c < 12; ++c)
        g += bf2f(xn[(size_t)tok * 1024 + c]) * ve_gate_w[kvh * 12 + c];
      g = 3.f / (1.f + __expf(-g));
      const float* ver = ve_tab + (size_t)ids[tok] * 256 + kl * 16;
#pragma unroll
      for (int i = 0; i < 16; ++i) v[i] += g * ver[i];
    }
    if (lane < 16) {
#pragma unroll
      for (int i = 0; i < 16; i += 4) {
        ushort4 u;
        u.x = f2bf(v[i]); u.y = f2bf(v[i + 1]); u.z = f2bf(v[i + 2]); u.w = f2bf(v[i + 3]);
        *reinterpret_cast<ushort4*>(vb + (size_t)tok * 256 + kl * 16 + i) = u;
      }
    }
  }
}

// ---------------- V transpose: vb[b][t][kv*64+d] -> vt[b*4+kv][d][t] -------

extern "C" __global__ __launch_bounds__(256)
void vtrans_kernel(const unsigned short* __restrict__ vb, unsigned short* __restrict__ vt) {
  __shared__ unsigned short tile[64][72];
  const int t0 = blockIdx.x << 6;
  const int bk = blockIdx.y;               // b*4 + kv
  const int tid = threadIdx.x;
  {
    const int r = tid >> 2, cs = (tid & 3) << 4;
    const unsigned short* src = vb + ((size_t)((bk >> 2) * 1024 + t0 + r)) * 256 + (bk & 3) * 64 + cs;
    *reinterpret_cast<uint4*>(&tile[r][cs]) = *reinterpret_cast<const uint4*>(src);
    *reinterpret_cast<uint4*>(&tile[r][cs + 8]) = *reinterpret_cast<const uint4*>(src + 8);
  }
  __syncthreads();
  {
    const int d = tid >> 2, ts = (tid & 3) << 4;
    unsigned int w[8];
#pragma unroll
    for (int i = 0; i < 8; ++i)
      w[i] = (unsigned int)tile[ts + 2 * i][d] | ((unsigned int)tile[ts + 2 * i + 1][d] << 16);
    unsigned short* dst = vt + ((size_t)bk * 64 + d) * 1024 + t0 + ts;
    uint4 u0; u0.x = w[0]; u0.y = w[1]; u0.z = w[2]; u0.w = w[3];
    uint4 u1; u1.x = w[4]; u1.y = w[5]; u1.z = w[6]; u1.w = w[7];
    *reinterpret_cast<uint4*>(dst) = u0;
    *reinterpret_cast<uint4*>(dst + 8) = u1;
  }
}

// --------------------------- flash attention -------------------------------

extern "C" __global__ __launch_bounds__(64)
void attn_kernel(const unsigned short* __restrict__ qb,
                 const unsigned short* __restrict__ kb,
                 const unsigned short* __restrict__ vt,
                 unsigned short* __restrict__ y, int W) {
  __shared__ unsigned short p_lds[16 * 32];
  const int lane = threadIdx.x;
  const int q0 = blockIdx.x << 4;
  const int h = blockIdx.y;
  const int b = blockIdx.z;
  const int kv = h >> 2;
  const int lr = lane & 15, lk = lane >> 4;

  bf16x8 qf0, qf1;
  {
    const unsigned short* qrow = qb + ((size_t)(b * 1024 + q0 + lr)) * 1024 + h * 64 + (lk << 3);
    qf0 = *reinterpret_cast<const bf16x8*>(qrow);
    qf1 = *reinterpret_cast<const bf16x8*>(qrow + 32);
  }
  f32x4 acc[4] = {};
  float m_run = -3e38f, l_run = 0.f;
  int kstart = q0 - W + 1; if (kstart < 0) kstart = 0;
  kstart &= ~31;
  const int qq = q0 + lr;

  for (int kb0 = kstart; kb0 < q0 + 16; kb0 += 32) {
    f32x4 st[2];
#pragma unroll
    for (int s = 0; s < 2; ++s) {
      const unsigned short* krow = kb + ((size_t)(b * 1024 + kb0 + (s << 4) + lr)) * 256 + kv * 64 + (lk << 3);
      bf16x8 kf0 = *reinterpret_cast<const bf16x8*>(krow);
      bf16x8 kf1 = *reinterpret_cast<const bf16x8*>(krow + 32);
      f32x4 z = {0.f, 0.f, 0.f, 0.f};
      z = __builtin_amdgcn_mfma_f32_16x16x32_bf16(kf0, qf0, z, 0, 0, 0);
      st[s] = __builtin_amdgcn_mfma_f32_16x16x32_bf16(kf1, qf1, z, 0, 0, 0);
    }
    float sv[8];
    float bm = -3e38f;
#pragma unroll
    for (int s = 0; s < 2; ++s)
#pragma unroll
      for (int j = 0; j < 4; ++j) {
        const int key = kb0 + (s << 4) + (lk << 2) + j;
        const bool valid = (key <= qq) && (qq - key < W);
        const float xx = valid ? st[s][j] : -3e38f;
        sv[s * 4 + j] = xx;
        bm = fmaxf(bm, xx);
      }
    bm = fmaxf(bm, __shfl_xor(bm, 16));
    bm = fmaxf(bm, __shfl_xor(bm, 32));
    const float m_new = fmaxf(m_run, bm);
    const float alpha = __expf(m_run - m_new);
    float psum = 0.f;
    unsigned short pbv[8];
#pragma unroll
    for (int s = 0; s < 2; ++s)
#pragma unroll
      for (int j = 0; j < 4; ++j) {
        const int key = kb0 + (s << 4) + (lk << 2) + j;
        const bool valid = (key <= qq) && (qq - key < W);
        const float pv = valid ? __expf(sv[s * 4 + j] - m_new) : 0.f;
        psum += pv;
        pbv[s * 4 + j] = f2bf(pv);
      }
    psum += __shfl_xor(psum, 16);
    psum += __shfl_xor(psum, 32);
    l_run = l_run * alpha + psum;
    m_run = m_new;

    __syncthreads();  // WAR vs previous iteration's reads
    {
      ushort4 u0, u1;
      u0.x = pbv[0]; u0.y = pbv[1]; u0.z = pbv[2]; u0.w = pbv[3];
      u1.x = pbv[4]; u1.y = pbv[5]; u1.z = pbv[6]; u1.w = pbv[7];
      *reinterpret_cast<ushort4*>(p_lds + lr * 32 + (lk << 2)) = u0;
      *reinterpret_cast<ushort4*>(p_lds + lr * 32 + 16 + (lk << 2)) = u1;
    }
    __syncthreads();
    const bf16x8 pf = *reinterpret_cast<const bf16x8*>(p_lds + lr * 32 + (lk << 3));
    float al[4];
#pragma unroll
    for (int j = 0; j < 4; ++j) al[j] = __shfl(alpha, (lk << 2) + j);
#pragma unroll
    for (int d = 0; d < 4; ++d) {
      const unsigned short* vrow = vt + ((size_t)((b * 4 + kv) * 64 + (d << 4) + lr)) * 1024 + kb0 + (lk << 3);
      const bf16x8 vf = *reinterpret_cast<const bf16x8*>(vrow);
#pragma unroll
      for (int j = 0; j < 4; ++j) acc[d][j] *= al[j];
      acc[d] = __builtin_amdgcn_mfma_f32_16x16x32_bf16(pf, vf, acc[d], 0, 0, 0);
    }
  }
  float linv[4];
#pragma unroll
  for (int j = 0; j < 4; ++j) linv[j] = 1.f / __shfl(l_run, (lk << 2) + j);
#pragma unroll
  for (int d = 0; d < 4; ++d)
#pragma unroll
    for (int j = 0; j < 4; ++j) {
      const int qrow = q0 + (lk << 2) + j;
      y[((size_t)(b * 1024 + qrow)) * 1024 + h * 64 + (d << 4) + lr] = f2bf(acc[d][j] * linv[j]);
    }
}

// ----------------------- gemm512: 128x128 / 8 waves ------------------------
// C[M,N] = A[M,K] bf16 @ Bw[N,K]^T. 512 threads, 8 waves (wr=wid>>2, wc=wid&3),
// per-wave 64x32 output -> acc[4][2] = 32 AGPRs/wave (occupancy lever).
// Staging: thread covers row=tid>>2 (0..127), ch=(tid&3)*8; one gload16 per
// operand per K-step (512x16B = 128x32 tile); LDS dest tid*16B = wave-uniform
// base + lane*16 (HW constraint OK). R5 schedule: stage(t+1) before MFMA, one
// __syncthreads per K-step. C^T operand-swapped epilogue (quad spans N).
// EPI: 0 f32 partial plane z, 2 relu^2->bf16, 3 softcap->f32.
// XCD swizzle when nwg%8==0.

template <int EPI>
__global__ __launch_bounds__(512)
void gemm512(const unsigned short* __restrict__ A,
             const unsigned short* __restrict__ Bw,
             void* __restrict__ Cout,
             int M, int N, int K, int kchunk) {
  __shared__ unsigned short sA[2][128 * 32];
  __shared__ unsigned short sB[2][128 * 32];
  const int tid = threadIdx.x;

  int flat = blockIdx.x + gridDim.x * blockIdx.y;
  const int nwg = gridDim.x * gridDim.y;
  if ((nwg & 7) == 0) flat = (flat & 7) * (nwg >> 3) + (flat >> 3);
  const int m0 = (flat % gridDim.x) << 7;
  const int n0 = (flat / gridDim.x) << 7;
  const int k_begin = blockIdx.z * kchunk;
  int k_end = k_begin + kchunk; if (k_end > K) k_end = K;

  const int wid = tid >> 6, lane = tid & 63;
  const int wr = wid >> 2, wc = wid & 3;           // 2 x 4 wave grid
  const int lr = lane & 15, lk = lane >> 4;

  // staging geometry: row=tid>>2 (0..127), ch=(tid&3)*8
  const int row0 = tid >> 2, ch0 = (tid & 3) << 3;
  const unsigned short* gA = A + (size_t)(m0 + row0) * K + ch0;
  const unsigned short* gB = Bw + (size_t)(n0 + row0) * K + ch0;

  auto stage = [&](int buf, int k0) {
    gload16(gA + k0, sA[buf] + tid * 8);
    gload16(gB + k0, sB[buf] + tid * 8);
  };

  f32x4 acc[4][2] = {};
  int cur = 0;
  stage(0, k_begin);
  __syncthreads();                        // drain prologue stage
  for (int k0 = k_begin; k0 < k_end; k0 += 32) {
    bf16x8 af[4], bfr[2];
#pragma unroll
    for (int i = 0; i < 4; ++i)
      af[i] = *reinterpret_cast<const bf16x8*>(sA[cur] + ((wr << 6) + (i << 4) + lr) * 32 + (lk << 3));
#pragma unroll
    for (int j = 0; j < 2; ++j)
      bfr[j] = *reinterpret_cast<const bf16x8*>(sB[cur] + ((wc << 5) + (j << 4) + lr) * 32 + (lk << 3));
    const int nxt = k0 + 32;
    if (nxt < k_end) stage(cur ^ 1, nxt);
#pragma unroll
    for (int i = 0; i < 4; ++i)
#pragma unroll
      for (int j = 0; j < 2; ++j)
        acc[i][j] = __builtin_amdgcn_mfma_f32_16x16x32_bf16(bfr[j], af[i], acc[i][j], 0, 0, 0);
    __syncthreads();                      // drains next-stage vmcnt + WAR
    cur ^= 1;
  }
  // C^T fragments: m = mbase + i*16; n = nbase + j*16 + e (quad along N)
  const int mbase = m0 + (wr << 6) + lr;
  const int nbase = n0 + (wc << 5) + (lk << 2);
  float* outF = (float*)Cout + (size_t)blockIdx.z * M * N;
#pragma unroll
  for (int i = 0; i < 4; ++i)
#pragma unroll
    for (int j = 0; j < 2; ++j) {
      const int m = mbase + (i << 4);
      const int n = nbase + (j << 4);
      const size_t off = (size_t)m * N + n;
      f32x4 v = acc[i][j];
      if (EPI == 0) {
        *reinterpret_cast<f32x4*>(outF + off) = v;
      } else if (EPI == 2) {
        ushort4 u;
        float r0 = v[0] > 0.f ? v[0] : 0.f;
        float r1 = v[1] > 0.f ? v[1] : 0.f;
        float r2 = v[2] > 0.f ? v[2] : 0.f;
        float r3 = v[3] > 0.f ? v[3] : 0.f;
        u.x = f2bf(r0 * r0); u.y = f2bf(r1 * r1);
        u.z = f2bf(r2 * r2); u.w = f2bf(r3 * r3);
        *reinterpret_cast<ushort4*>((unsigned short*)Cout + off) = u;
      } else {
        f32x4 o;
#pragma unroll
        for (int e = 0; e < 4; ++e) {
          const float ex = __expf(v[e] * (2.f / 15.f));
          o[e] = 15.f - 30.f / (ex + 1.f);
        }
        *reinterpret_cast<f32x4*>((float*)Cout + off) = o;
      }
    }
}

// ----------------- legacy 256-thread GEMM (Wo only: 128x64) ----------------

template <int EPI, int NJ>
__global__ __launch_bounds__(256)
void gemm_bf16(const unsigned short* __restrict__ A,
               const unsigned short* __restrict__ Bw,
               const float* __restrict__ Cin, void* __restrict__ Cout,
               int M, int N, int K, int kchunk) {
  constexpr int BN = NJ * 32;
  __shared__ unsigned short sA[2][128 * 32];
  __shared__ unsigned short sB[2][BN * 32];
  const int tid = threadIdx.x;

  int flat = blockIdx.x + gridDim.x * blockIdx.y;
  const int nwg = gridDim.x * gridDim.y;
  if ((nwg & 7) == 0) flat = (flat & 7) * (nwg >> 3) + (flat >> 3);
  const int m0 = (flat % gridDim.x) << 7;
  const int n0 = (flat / gridDim.x) * BN;
  const int k_begin = blockIdx.z * kchunk;
  int k_end = k_begin + kchunk; if (k_end > K) k_end = K;

  const int wid = tid >> 6, lane = tid & 63;
  const int wr = wid >> 1, wc = wid & 1;
  const int lr = lane & 15, lk = lane >> 4;

  const int row0 = tid >> 2, ch0 = (tid & 3) << 3;
  const unsigned short* gA0 = A + (size_t)(m0 + row0) * K + ch0;
  const unsigned short* gA1 = gA0 + (size_t)64 * K;
  const unsigned short* gB0 = Bw + (size_t)(n0 + row0) * K + ch0;
  const int lofs = wid << 9;

  auto stage = [&](int buf, int k0) {
    gload16(gA0 + k0, sA[buf] + lofs);
    gload16(gA1 + k0, sA[buf] + lofs + 2048);
    gload16(gB0 + k0, sB[buf] + lofs);
  };

  f32x4 acc[4][NJ] = {};
  int cur = 0;
  stage(0, k_begin);
  __syncthreads();
  for (int k0 = k_begin; k0 < k_end; k0 += 32) {
    bf16x8 af[4], bfr[NJ];
#pragma unroll
    for (int i = 0; i < 4; ++i)
      af[i] = *reinterpret_cast<const bf16x8*>(sA[cur] + ((wr << 6) + (i << 4) + lr) * 32 + (lk << 3));
#pragma unroll
    for (int j = 0; j < NJ; ++j)
      bfr[j] = *reinterpret_cast<const bf16x8*>(sB[cur] + (wc * (BN / 2) + (j << 4) + lr) * 32 + (lk << 3));
    const int nxt = k0 + 32;
    if (nxt < k_end) stage(cur ^ 1, nxt);
#pragma unroll
    for (int i = 0; i < 4; ++i)
#pragma unroll
      for (int j = 0; j < NJ; ++j)
        acc[i][j] = __builtin_amdgcn_mfma_f32_16x16x32_bf16(bfr[j], af[i], acc[i][j], 0, 0, 0);
    __syncthreads();
    cur ^= 1;
  }
  const int mbase = m0 + (wr << 6) + lr;
  const int nbase = n0 + wc * (BN / 2) + (lk << 2);
  float* outF = (float*)Cout + (size_t)blockIdx.z * M * N;
#pragma unroll
  for (int i = 0; i < 4; ++i)
#pragma unroll
    for (int j = 0; j < NJ; ++j) {
      const int m = mbase + (i << 4);
      const int n = nbase + (j << 4);
      const size_t off = (size_t)m * N + n;
      *reinterpret_cast<f32x4*>(outF + off) = acc[i][j];
    }
  (void)Cin;
}

// ------------------------------- launcher ----------------------------------

extern "C" void kernel_launch(void* const* d_in, const int* in_sizes, int n_in,
                              void* d_out, int out_size, void* d_ws, size_t ws_size,
                              hipStream_t stream) {
  (void)in_sizes; (void)n_in; (void)out_size; (void)ws_size;
  const int*   ids  = (const int*)  d_in[0];
  const float* wte  = (const float*)d_in[1];
  const float* Wq   = (const float*)d_in[2];
  const float* Wk   = (const float*)d_in[3];
  const float* Wv   = (const float*)d_in[4];
  const float* Wo   = (const float*)d_in[5];
  const float* Wfc  = (const float*)d_in[6];
  const float* Wmp  = (const float*)d_in[7];
  const float* VeT  = (const float*)d_in[8];
  const float* VeG  = (const float*)d_in[9];
  const float* LmW  = (const float*)d_in[10];
  const float* ResC = (const float*)d_in[11];
  const float* X0C  = (const float*)d_in[12];
  const float* SmW  = (const float*)d_in[13];
  const float* SmL  = (const float*)d_in[14];

  char* p = (char*)d_ws;
  auto alloc = [&](size_t bytes) -> char* {
    char* r = p; p += (bytes + 255) & ~(size_t)255; return r;
  };
  float* x  = (float*)alloc((size_t)2048 * 1024 * 4);
  float* x0 = (float*)alloc((size_t)2048 * 1024 * 4);
  unsigned short* xn = (unsigned short*)alloc((size_t)2048 * 1024 * 2);
  unsigned short* hidden = (unsigned short*)alloc((size_t)2048 * 4096 * 2);
  float* qkvp = (float*)alloc((size_t)2 * 2048 * 1536 * 4);   // qkv split-K partials
  float* wop  = (float*)alloc((size_t)2 * 2048 * 1024 * 4);   // Wo split-K partials
  float* mpp  = (float*)alloc((size_t)4 * 2048 * 1024 * 4);   // MP split-K partials
  unsigned short* qbuf = (unsigned short*)alloc((size_t)2048 * 1024 * 2);
  unsigned short* kbuf = (unsigned short*)alloc((size_t)2048 * 256 * 2);
  unsigned short* vbuf = (unsigned short*)alloc((size_t)2048 * 256 * 2);
  unsigned short* vtb  = (unsigned short*)alloc((size_t)2048 * 256 * 2);
  unsigned short* ybuf = (unsigned short*)alloc((size_t)2048 * 1024 * 2);
  float* cost = (float*)alloc((size_t)1024 * 32 * 4);
  float* sint = (float*)alloc((size_t)1024 * 32 * 4);
  unsigned short* wqkv = (unsigned short*)alloc((size_t)6 * 1536 * 1024 * 2);
  unsigned short* wo   = (unsigned short*)alloc((size_t)6 * 1024 * 1024 * 2);
  unsigned short* wfc  = (unsigned short*)alloc((size_t)6 * 4096 * 1024 * 2);
  unsigned short* wmp  = (unsigned short*)alloc((size_t)6 * 1024 * 4096 * 2);
  unsigned short* wlm  = (unsigned short*)alloc((size_t)32000 * 1024 * 2);

  prep_weights_kernel<<<48256, 256, 0, stream>>>(Wq, Wk, Wv, Wo, Wfc, Wmp, LmW,
                                                 wqkv, wo, wfc, wmp, wlm);
  rope_tab_kernel<<<128, 256, 0, stream>>>(cost, sint);
  embed_kernel<<<512, 256, 0, stream>>>(ids, wte, SmW, SmL, ResC, X0C, x, x0, xn);

  static const int WIN[6] = {256, 1024, 256, 1024, 256, 1024};
  for (int l = 0; l < 6; ++l) {
    if (l > 0)
      rmsnorm_kernel<<<512, 256, 0, stream>>>(x, x0, mpp, 4, ResC, X0C, l, 1, xn);
    // QKV: split-K x2 -> two partial planes (summed inside qkv_post)
    gemm512<0><<<dim3(16, 12, 2), 512, 0, stream>>>(xn, wqkv + (size_t)l * 1536 * 1024,
                                                    qkvp, 2048, 1536, 1024, 512);
    const float* vtab = nullptr; const float* vgw = nullptr;
    if (l == 1 || l == 3 || l == 5) {
      const int vi = (l - 1) / 2;
      vtab = VeT + (size_t)vi * 32000 * 256;
      vgw  = VeG + vi * 48;
    }
    qkv_post_kernel<<<512, 256, 0, stream>>>(qkvp, qkvp + (size_t)2048 * 1536, xn, ids,
                                             vtab, vgw, cost, sint, qbuf, kbuf, vbuf);
    vtrans_kernel<<<dim3(16, 8), 256, 0, stream>>>(vbuf, vtb);
    attn_kernel<<<dim3(64, 16, 2), 64, 0, stream>>>(qbuf, kbuf, vtb, ybuf, WIN[l]);
    // Wo: split-K x2 -> partials (reduced + added to x by next rmsnorm)
    gemm_bf16<0, 2><<<dim3(16, 16, 2), 256, 0, stream>>>(ybuf, wo + (size_t)l * 1024 * 1024,
                                                         nullptr, wop, 2048, 1024, 1024, 512);
    rmsnorm_kernel<<<512, 256, 0, stream>>>(x, x0, wop, 2, ResC, X0C, l, 0, xn);
    gemm512<2><<<dim3(16, 32), 512, 0, stream>>>(xn, wfc + (size_t)l * 4096 * 1024,
                                                 hidden, 2048, 4096, 1024, 1024);
    // MP: split-K x4 (K=4096) -> partials (reduced by next layer's rmsnorm)
    gemm512<0><<<dim3(16, 8, 4), 512, 0, stream>>>(hidden, wmp + (size_t)l * 1024 * 4096,
                                                   mpp, 2048, 1024, 4096, 1024);
  }
  rmsnorm_kernel<<<512, 256, 0, stream>>>(x, x0, mpp, 4, ResC, X0C, 0, 0, xn);
  gemm512<3><<<dim3(16, 250), 512, 0, stream>>>(xn, wlm, (float*)d_out,
                                                2048, 32000, 1024, 1024);
}